// Round 5
// baseline (450.370 us; speedup 1.0000x reference)
//
#include <hip/hip_runtime.h>
#include <cstddef>
#include <cstdint>

// ---------------------------------------------------------------------------
// GraphNeuralNetworkRiskManager: 2x GraphConv (sum-agg) + GAT attention + FC
// N=50000 nodes, E=800000 edges, F_IN=HID=128, F_OUT=2.
//
// Round 5: mgemm rebuilt against the round-4 latency diagnosis:
//   - W pre-split (hi/lo bf16) + pre-transposed [j][k] by wsplit_kernel (once),
//     so the GEMM W-prologue is 16B vector loads, zero VALU.
//   - 128-row tiles, 8 acc chains/wave, explicit register double-buffer with
//     LOAD(rf+1) issued before COMPUTE(rf)  -> ~24-MFMA prefetch distance.
//   - attn: online-softmax merges max+denom passes (3 -> 2 edge passes).
// Node tensors remain bf16 hi+lo pairs (2^-18 rel); softmax fp32.
// ---------------------------------------------------------------------------

typedef __attribute__((ext_vector_type(8))) short short8;
typedef __attribute__((ext_vector_type(4))) float f32x4;

__device__ __forceinline__ ushort f2b(float f) {       // fp32 -> bf16 bits, RNE
  uint32_t u = __float_as_uint(f);
  u += 0x7fffu + ((u >> 16) & 1u);
  return (ushort)(u >> 16);
}
__device__ __forceinline__ float b2f(ushort h) {       // bf16 bits -> fp32
  return __uint_as_float(((uint32_t)h) << 16);
}

// ---------------- fp32 -> (hi, lo) bf16 split of x ----------------

__global__ __launch_bounds__(256) void split_kernel(
    const float* __restrict__ in, ushort* __restrict__ hi,
    ushort* __restrict__ lo, int n) {
  int i = (blockIdx.x * blockDim.x + threadIdx.x) * 8;
  if (i >= n) return;
  float4 v0 = *(const float4*)(in + i);
  float4 v1 = *(const float4*)(in + i + 4);
  float v[8] = {v0.x, v0.y, v0.z, v0.w, v1.x, v1.y, v1.z, v1.w};
  short8 h, l;
  #pragma unroll
  for (int b = 0; b < 8; ++b) {
    ushort hh = f2b(v[b]);
    h[b] = (short)hh;
    l[b] = (short)f2b(v[b] - b2f(hh));
  }
  *(short8*)(hi + i) = h;
  *(short8*)(lo + i) = l;
}

// ---------------- W split+transpose: W[k][j] fp32 -> WhT/WlT[m][j][k] bf16 ----------------
// One block per matrix (5 blocks). LDS transpose, coalesced in, short8 out.

__global__ __launch_bounds__(256) void wsplit_kernel(
    const float* __restrict__ W0, const float* __restrict__ W1,
    const float* __restrict__ W2, const float* __restrict__ W3,
    const float* __restrict__ W4,
    ushort* __restrict__ WhT, ushort* __restrict__ WlT) {
  __shared__ float tile[128][128];
  int m = blockIdx.x;
  const float* W = (m == 0) ? W0 : (m == 1) ? W1 : (m == 2) ? W2 : (m == 3) ? W3 : W4;
  int t = threadIdx.x;
  #pragma unroll
  for (int i = 0; i < 64; ++i) {
    int idx = i * 256 + t;                 // coalesced read
    tile[idx >> 7][idx & 127] = W[idx];
  }
  __syncthreads();
  int j = t >> 1, k0 = (t & 1) * 64;
  size_t obase = (size_t)m * 16384 + (size_t)j * 128 + k0;
  #pragma unroll
  for (int c = 0; c < 8; ++c) {
    short8 h, l;
    #pragma unroll
    for (int b = 0; b < 8; ++b) {
      float v = tile[k0 + c * 8 + b][j];
      ushort hh = f2b(v);
      h[b] = (short)hh;
      l[b] = (short)f2b(v - b2f(hh));
    }
    *(short8*)(WhT + obase + c * 8) = h;
    *(short8*)(WlT + obase + c * 8) = l;
  }
}

// ---------------- CSR build ----------------

__global__ void hist_kernel(const int* __restrict__ ei, int E, int* __restrict__ cnt) {
  int e = blockIdx.x * blockDim.x + threadIdx.x;
  if (e < E) atomicAdd(&cnt[ei[E + e]], 1);  // dst = ei[E+e]
}

// exclusive prefix sum of cnt[0..n-1] -> ofs[0..n], single block of 1024
__global__ void scan_kernel(const int* __restrict__ cnt, int* __restrict__ ofs, int n) {
  __shared__ int wsum[16];
  __shared__ int carry;
  int tid = threadIdx.x;
  int lane = tid & 63;
  int wid = tid >> 6;
  if (tid == 0) carry = 0;
  __syncthreads();
  for (int base = 0; base < n; base += 1024) {
    int i = base + tid;
    int v = (i < n) ? cnt[i] : 0;
    int x = v;
    #pragma unroll
    for (int d = 1; d < 64; d <<= 1) {
      int y = __shfl_up(x, d);
      if (lane >= d) x += y;
    }
    if (lane == 63) wsum[wid] = x;
    __syncthreads();
    if (wid == 0) {
      int s = (lane < 16) ? wsum[lane] : 0;
      #pragma unroll
      for (int d = 1; d < 16; d <<= 1) {
        int y = __shfl_up(s, d);
        if (lane >= d) s += y;
      }
      if (lane < 16) wsum[lane] = s;
    }
    __syncthreads();
    int waveoff = (wid > 0) ? wsum[wid - 1] : 0;
    int incl = x + waveoff;
    int total = wsum[15];
    int c = carry;
    if (i < n) ofs[i] = c + incl - v;
    __syncthreads();
    if (tid == 0) carry = c + total;
    __syncthreads();
  }
  if (tid == 0) ofs[n] = carry;
}

__global__ void scatter_kernel(const int* __restrict__ ei, int E,
                               const int* __restrict__ ofs, int* __restrict__ cur,
                               int* __restrict__ csr) {
  int e = blockIdx.x * blockDim.x + threadIdx.x;
  if (e < E) {
    int d = ei[E + e];
    int p = ofs[d] + atomicAdd(&cur[d], 1);
    csr[p] = ei[e];  // src
  }
}

// ---------------- CSR sum-aggregation, 4-edge groups ----------------

__global__ __launch_bounds__(256) void agg_kernel(
    const ushort* __restrict__ Xh, const int* __restrict__ csr,
    const int* __restrict__ ofs, ushort* __restrict__ Gh,
    ushort* __restrict__ Gl, int N) {
  int node = (blockIdx.x * blockDim.x + threadIdx.x) >> 6;
  int lane = threadIdx.x & 63;
  if (node >= N) return;
  int g = lane >> 4, q = lane & 15;
  int beg = ofs[node], end = ofs[node + 1];
  float a[8] = {};
  for (int p = beg + g; p < end; p += 4) {
    int s = csr[p];
    short8 v = *(const short8*)(Xh + (size_t)s * 128 + q * 8);
    #pragma unroll
    for (int b = 0; b < 8; ++b) a[b] += b2f((ushort)v[b]);
  }
  #pragma unroll
  for (int b = 0; b < 8; ++b) {
    a[b] += __shfl_xor(a[b], 16);
    a[b] += __shfl_xor(a[b], 32);
  }
  if (lane < 16) {
    short8 h, l;
    #pragma unroll
    for (int b = 0; b < 8; ++b) {
      ushort hh = f2b(a[b]);
      h[b] = (short)hh;
      l[b] = (short)f2b(a[b] - b2f(hh));
    }
    *(short8*)(Gh + (size_t)node * 128 + q * 8) = h;
    *(short8*)(Gl + (size_t)node * 128 + q * 8) = l;
  }
}

// ---------------- bf16x3 MFMA GEMM: C = act(A1@W1 [+ A2@W2] + b) ----------------
// 128-row tile/block, 512 threads = 8 waves, wave w owns cols [16w,16w+16).
// W pre-split/transposed: 16B loads. Register double-buffer over rf.
// A frag (16x16x32): lane l -> row (l&15), k = (l>>4)*8 + b.
// D frag: col = l&15, row = (l>>4)*4 + reg   [validated rounds 2-4].

#define LOAD_A(RF, BH, BL)                                          \
  {                                                                 \
    int row_ = rowBase + (RF) * 16 + (l & 15);                      \
    if (row_ >= M) row_ = M - 1;                                    \
    size_t base_ = (size_t)row_ * 128 + krow0;                      \
    _Pragma("unroll")                                               \
    for (int ks = 0; ks < 4; ++ks) {                                \
      BH[0][ks] = *(const short8*)(A1h + base_ + ks * 32);          \
      BL[0][ks] = *(const short8*)(A1l + base_ + ks * 32);          \
      if (S > 1) {                                                  \
        BH[1][ks] = *(const short8*)(A2h + base_ + ks * 32);        \
        BL[1][ks] = *(const short8*)(A2l + base_ + ks * 32);        \
      }                                                             \
    }                                                               \
  }

#define COMPUTE(RF, BH, BL)                                                                       \
  _Pragma("unroll")                                                                               \
  for (int s = 0; s < S; ++s) {                                                                   \
    _Pragma("unroll")                                                                             \
    for (int ks = 0; ks < 4; ++ks) {                                                              \
      acc[RF] = __builtin_amdgcn_mfma_f32_16x16x32_bf16(BL[s][ks], wh[s][ks], acc[RF], 0, 0, 0);  \
      acc[RF] = __builtin_amdgcn_mfma_f32_16x16x32_bf16(BH[s][ks], wl[s][ks], acc[RF], 0, 0, 0);  \
      acc[RF] = __builtin_amdgcn_mfma_f32_16x16x32_bf16(BH[s][ks], wh[s][ks], acc[RF], 0, 0, 0);  \
    }                                                                                             \
  }

template <int S, bool RELU, bool BIAS>
__global__ __launch_bounds__(512, 2) void mgemm_kernel(
    const ushort* __restrict__ A1h, const ushort* __restrict__ A1l,
    const ushort* __restrict__ A2h, const ushort* __restrict__ A2l,
    const ushort* __restrict__ WhT, const ushort* __restrict__ WlT,
    const float* __restrict__ bias,
    ushort* __restrict__ Ch, ushort* __restrict__ Cl, int M) {
  int l = threadIdx.x & 63;
  int w = threadIdx.x >> 6;
  int j = (w << 4) + (l & 15);      // output column
  int krow0 = (l >> 4) * 8;         // k offset within 32-wide k-step
  int rowBase = blockIdx.x * 128;

  // W fragments: straight 16B loads from pre-split transposed W
  short8 wh[S][4], wl[S][4];
  #pragma unroll
  for (int s = 0; s < S; ++s) {
    #pragma unroll
    for (int ks = 0; ks < 4; ++ks) {
      size_t wb = (size_t)s * 16384 + (size_t)j * 128 + ks * 32 + krow0;
      wh[s][ks] = *(const short8*)(WhT + wb);
      wl[s][ks] = *(const short8*)(WlT + wb);
    }
  }

  f32x4 acc[8];
  #pragma unroll
  for (int i = 0; i < 8; ++i) acc[i] = (f32x4){0.f, 0.f, 0.f, 0.f};

  short8 b0h[2][4], b0l[2][4], b1h[2][4], b1l[2][4];

  LOAD_A(0, b0h, b0l)
  LOAD_A(1, b1h, b1l)  COMPUTE(0, b0h, b0l)
  LOAD_A(2, b0h, b0l)  COMPUTE(1, b1h, b1l)
  LOAD_A(3, b1h, b1l)  COMPUTE(2, b0h, b0l)
  LOAD_A(4, b0h, b0l)  COMPUTE(3, b1h, b1l)
  LOAD_A(5, b1h, b1l)  COMPUTE(4, b0h, b0l)
  LOAD_A(6, b0h, b0l)  COMPUTE(5, b1h, b1l)
  LOAD_A(7, b1h, b1l)  COMPUTE(6, b0h, b0l)
                       COMPUTE(7, b1h, b1l)

  float bj = BIAS ? bias[j] : 0.f;
  #pragma unroll
  for (int rf = 0; rf < 8; ++rf) {
    int rbase = rowBase + rf * 16 + (l >> 4) * 4;
    #pragma unroll
    for (int r = 0; r < 4; ++r) {
      int row = rbase + r;
      if (row < M) {
        float v = acc[rf][r];
        if (BIAS) v += bj;
        if (RELU) v = fmaxf(v, 0.f);
        ushort h = f2b(v);
        Ch[(size_t)row * 128 + j] = h;
        Cl[(size_t)row * 128 + j] = f2b(v - b2f(h));
      }
    }
  }
}

// ---------------- per-node dots: s_src = ht.a_src, s_dst = ht.a_dst ----------------

__global__ __launch_bounds__(256) void dots_kernel(
    const ushort* __restrict__ HTh, const ushort* __restrict__ HTl,
    const float* __restrict__ a_src, const float* __restrict__ a_dst,
    float* __restrict__ ssrc, float* __restrict__ sdst, int N) {
  int n = (blockIdx.x * blockDim.x + threadIdx.x) >> 6;
  int lane = threadIdx.x & 63;
  if (n >= N) return;
  uint uh = ((const uint*)(HTh + (size_t)n * 128))[lane];
  uint ul = ((const uint*)(HTl + (size_t)n * 128))[lane];
  float h0 = b2f((ushort)(uh & 0xffff)) + b2f((ushort)(ul & 0xffff));
  float h1 = b2f((ushort)(uh >> 16)) + b2f((ushort)(ul >> 16));
  float vs = h0 * a_src[2 * lane] + h1 * a_src[2 * lane + 1];
  float vd = h0 * a_dst[2 * lane] + h1 * a_dst[2 * lane + 1];
  #pragma unroll
  for (int d = 32; d > 0; d >>= 1) {
    vs += __shfl_xor(vs, d);
    vd += __shfl_xor(vd, d);
  }
  if (lane == 0) { ssrc[n] = vs; sdst[n] = vd; }
}

// ---------------- fused attention: online segment softmax + weighted PV ----------------

__global__ __launch_bounds__(256) void attn_kernel(
    const ushort* __restrict__ HTh, const int* __restrict__ csr,
    const int* __restrict__ ofs, const float* __restrict__ ssrc,
    const float* __restrict__ sdst, float* __restrict__ outh, int N) {
  int n = (blockIdx.x * blockDim.x + threadIdx.x) >> 6;
  int lane = threadIdx.x & 63;
  if (n >= N) return;
  int beg = ofs[n], end = ofs[n + 1];
  float sd = sdst[n];

  // phase 1: online max + denom in a single edge pass
  float m = -3.4e38f, ssum = 0.f;
  for (int p = beg + lane; p < end; p += 64) {
    float e = ssrc[csr[p]] + sd;
    e = (e >= 0.f) ? e : 0.2f * e;
    float nm = fmaxf(m, e);
    ssum = ssum * __expf(m - nm) + __expf(e - nm);
    m = nm;
  }
  #pragma unroll
  for (int d = 32; d > 0; d >>= 1) {
    float om = __shfl_xor(m, d);
    float os = __shfl_xor(ssum, d);
    float nm = fmaxf(m, om);
    ssum = ssum * __expf(m - nm) + os * __expf(om - nm);
    m = nm;
  }
  float inv = 1.0f / (ssum + 1e-16f);

  // phase 2: weighted PV, 4-edge groups with 16B loads
  int g = lane >> 4, q = lane & 15;
  float a[8] = {};
  for (int p = beg + g; p < end; p += 4) {
    int s = csr[p];
    float e = ssrc[s] + sd;
    e = (e >= 0.f) ? e : 0.2f * e;
    float wgt = __expf(e - m) * inv;
    short8 v = *(const short8*)(HTh + (size_t)s * 128 + q * 8);
    #pragma unroll
    for (int b = 0; b < 8; ++b) a[b] += wgt * b2f((ushort)v[b]);
  }
  #pragma unroll
  for (int b = 0; b < 8; ++b) {
    a[b] += __shfl_xor(a[b], 16);
    a[b] += __shfl_xor(a[b], 32);
  }
  if (lane < 16) {
    float4 o0 = {a[0], a[1], a[2], a[3]};
    float4 o1 = {a[4], a[5], a[6], a[7]};
    *(float4*)(outh + (size_t)n * 128 + q * 8) = o0;
    *(float4*)(outh + (size_t)n * 128 + q * 8 + 4) = o1;
  }
}

// ---------------- final FC: out = out_h @ Wfc + bfc  (128 -> 2) ----------------

__global__ __launch_bounds__(256) void fc_kernel(
    const float* __restrict__ H, const float* __restrict__ Wfc,
    const float* __restrict__ bfc, float* __restrict__ out, int N) {
  int n = (blockIdx.x * blockDim.x + threadIdx.x) >> 6;
  int lane = threadIdx.x & 63;
  if (n >= N) return;
  float h0 = H[(size_t)n * 128 + lane];
  float h1 = H[(size_t)n * 128 + 64 + lane];
  float o0 = h0 * Wfc[lane * 2 + 0] + h1 * Wfc[(lane + 64) * 2 + 0];
  float o1 = h0 * Wfc[lane * 2 + 1] + h1 * Wfc[(lane + 64) * 2 + 1];
  #pragma unroll
  for (int d = 32; d > 0; d >>= 1) {
    o0 += __shfl_xor(o0, d);
    o1 += __shfl_xor(o1, d);
  }
  if (lane == 0) {
    out[(size_t)n * 2 + 0] = o0 + bfc[0];
    out[(size_t)n * 2 + 1] = o1 + bfc[1];
  }
}

// ---------------- launch ----------------

static inline size_t align_up(size_t x, size_t a) { return (x + a - 1) & ~(a - 1); }

extern "C" void kernel_launch(void* const* d_in, const int* in_sizes, int n_in,
                              void* d_out, int out_size, void* d_ws, size_t ws_size,
                              hipStream_t stream) {
  const float* x     = (const float*)d_in[0];
  const int*   ei    = (const int*)d_in[1];
  const float* W1r   = (const float*)d_in[2];
  const float* W1n   = (const float*)d_in[3];
  const float* b1    = (const float*)d_in[4];
  const float* W2r   = (const float*)d_in[5];
  const float* W2n   = (const float*)d_in[6];
  const float* b2    = (const float*)d_in[7];
  const float* Wa    = (const float*)d_in[8];
  const float* a_src = (const float*)d_in[9];
  const float* a_dst = (const float*)d_in[10];
  const float* Wfc   = (const float*)d_in[11];
  const float* bfc   = (const float*)d_in[12];

  const int N = in_sizes[0] / 128;   // 50000
  const int E = in_sizes[1] / 2;     // 800000

  // workspace carve-up
  char* ws = (char*)d_ws;
  size_t off = 0;
  auto take = [&](size_t bytes) {
    char* p = ws + off;
    off = align_up(off + bytes, 256);
    return p;
  };
  const size_t NB = (size_t)N * 128 * 2;  // one bf16 node tensor (12.8 MB)
  int*    ofs  = (int*)take((size_t)(N + 1) * 4);
  int*    cnt  = (int*)take((size_t)N * 4);
  int*    cur  = (int*)take((size_t)N * 4);
  int*    csr  = (int*)take((size_t)E * 4);
  float*  ssrc = (float*)take((size_t)N * 4);
  float*  sdst = (float*)take((size_t)N * 4);
  ushort* whT  = (ushort*)take((size_t)5 * 16384 * 2);  // pre-split W hi
  ushort* wlT  = (ushort*)take((size_t)5 * 16384 * 2);  // pre-split W lo
  ushort* bA   = (ushort*)take(NB);   // x_hi  -> h2_hi
  ushort* bB   = (ushort*)take(NB);   // x_lo  -> h2_lo
  ushort* bC   = (ushort*)take(NB);   // g_hi  -> ht_hi
  ushort* bD   = (ushort*)take(NB);   // g_lo  -> ht_lo
  ushort* bE   = (ushort*)take(NB);   // h1_hi -.
  ushort* bF   = (ushort*)take(NB);   // h1_lo  }-> outh (fp32, spans E+F)
  float*  outh = (float*)bE;

  hipMemsetAsync(cnt, 0, (size_t)N * 4, stream);
  hipMemsetAsync(cur, 0, (size_t)N * 4, stream);

  const int edgeBlocks = (E + 255) / 256;
  const int nodeBlocks = (N + 3) / 4;     // 4 waves per 256-thread block
  const int gemmBlocks = (N + 127) / 128; // 128-row tiles
  const int splitBlocks = (N * 128 / 8 + 255) / 256;

  // W pre-split (mats: 0=W1r 1=W1n 2=W2r 3=W2n 4=Wa), x split, CSR build
  wsplit_kernel<<<5, 256, 0, stream>>>(W1r, W1n, W2r, W2n, Wa, whT, wlT);
  split_kernel<<<splitBlocks, 256, 0, stream>>>(x, bA, bB, N * 128);
  hist_kernel<<<edgeBlocks, 256, 0, stream>>>(ei, E, cnt);
  scan_kernel<<<1, 1024, 0, stream>>>(cnt, ofs, N);
  scatter_kernel<<<edgeBlocks, 256, 0, stream>>>(ei, E, ofs, cur, csr);

  // layer 1: agg1 = sum(x_hi); h1 = relu(x@W1r + agg1@W1n + b1)
  agg_kernel<<<nodeBlocks, 256, 0, stream>>>(bA, csr, ofs, bC, bD, N);
  mgemm_kernel<2, true, true><<<gemmBlocks, 512, 0, stream>>>(
      bA, bB, bC, bD, whT, wlT, b1, bE, bF, N);                    // h1 -> E,F

  // layer 2: agg2 = sum(h1_hi); h2 = relu(h1@W2r + agg2@W2n + b2)
  agg_kernel<<<nodeBlocks, 256, 0, stream>>>(bE, csr, ofs, bC, bD, N);
  mgemm_kernel<2, true, true><<<gemmBlocks, 512, 0, stream>>>(
      bE, bF, bC, bD, whT + 2 * 16384, wlT + 2 * 16384, b2, bA, bB, N);  // h2 -> A,B

  // attention transform: ht = h2@Wa -> C,D
  mgemm_kernel<1, false, false><<<gemmBlocks, 512, 0, stream>>>(
      bA, bB, nullptr, nullptr, whT + 4 * 16384, wlT + 4 * 16384,
      nullptr, bC, bD, N);
  dots_kernel<<<nodeBlocks, 256, 0, stream>>>(bC, bD, a_src, a_dst, ssrc, sdst, N);
  attn_kernel<<<nodeBlocks, 256, 0, stream>>>(bC, csr, ofs, ssrc, sdst, outh, N);

  // output FC
  fc_kernel<<<nodeBlocks, 256, 0, stream>>>(outh, Wfc, bfc, (float*)d_out, N);
}

// Round 6
// 353.522 us; speedup vs baseline: 1.2740x; 1.2740x over previous
//
#include <hip/hip_runtime.h>
#include <cstddef>
#include <cstdint>

// ---------------------------------------------------------------------------
// GraphNeuralNetworkRiskManager: 2x GraphConv (sum-agg) + GAT attention + FC
// N=50000 nodes, E=800000 edges, F_IN=HID=128, F_OUT=2.
//
// Round 6: mgemm rebuilt on the m97 pattern (round-5 post-mortem: compiler
// sank register prefetch, VGPR=56, latency-bound at 5% MfmaUtil):
//   - async global->LDS staging via global_load_lds width=16 (all A tensors),
//     one barrier, then ds_read_b128 + MFMA.
//   - XOR swizzle (row&7)<<4 applied to the GLOBAL source AND the LDS read
//     (linear LDS dest) -> conflict-free b128 reads at 256B row stride.
//   - W pre-split/transposed (hi/lo bf16), 16B register loads, unchanged.
// Node tensors bf16 hi+lo pairs (2^-18 rel); softmax fp32. bf16x3 MFMA.
// ---------------------------------------------------------------------------

typedef __attribute__((ext_vector_type(8))) short short8;
typedef __attribute__((ext_vector_type(4))) float f32x4;

__device__ __forceinline__ ushort f2b(float f) {       // fp32 -> bf16 bits, RNE
  uint32_t u = __float_as_uint(f);
  u += 0x7fffu + ((u >> 16) & 1u);
  return (ushort)(u >> 16);
}
__device__ __forceinline__ float b2f(ushort h) {       // bf16 bits -> fp32
  return __uint_as_float(((uint32_t)h) << 16);
}

__device__ __forceinline__ void gload_lds16(const void* g, void* l) {
  __builtin_amdgcn_global_load_lds(
      (const __attribute__((address_space(1))) void*)g,
      (__attribute__((address_space(3))) void*)l, 16, 0, 0);
}

// ---------------- fp32 -> (hi, lo) bf16 split of x ----------------

__global__ __launch_bounds__(256) void split_kernel(
    const float* __restrict__ in, ushort* __restrict__ hi,
    ushort* __restrict__ lo, int n) {
  int i = (blockIdx.x * blockDim.x + threadIdx.x) * 8;
  if (i >= n) return;
  float4 v0 = *(const float4*)(in + i);
  float4 v1 = *(const float4*)(in + i + 4);
  float v[8] = {v0.x, v0.y, v0.z, v0.w, v1.x, v1.y, v1.z, v1.w};
  short8 h, l;
  #pragma unroll
  for (int b = 0; b < 8; ++b) {
    ushort hh = f2b(v[b]);
    h[b] = (short)hh;
    l[b] = (short)f2b(v[b] - b2f(hh));
  }
  *(short8*)(hi + i) = h;
  *(short8*)(lo + i) = l;
}

// ---------------- W split+transpose: W[k][j] fp32 -> WhT/WlT[m][j][k] bf16 ----------------

__global__ __launch_bounds__(256) void wsplit_kernel(
    const float* __restrict__ W0, const float* __restrict__ W1,
    const float* __restrict__ W2, const float* __restrict__ W3,
    const float* __restrict__ W4,
    ushort* __restrict__ WhT, ushort* __restrict__ WlT) {
  __shared__ float tile[128][128];
  int m = blockIdx.x;
  const float* W = (m == 0) ? W0 : (m == 1) ? W1 : (m == 2) ? W2 : (m == 3) ? W3 : W4;
  int t = threadIdx.x;
  #pragma unroll
  for (int i = 0; i < 64; ++i) {
    int idx = i * 256 + t;                 // coalesced read
    tile[idx >> 7][idx & 127] = W[idx];
  }
  __syncthreads();
  int j = t >> 1, k0 = (t & 1) * 64;
  size_t obase = (size_t)m * 16384 + (size_t)j * 128 + k0;
  #pragma unroll
  for (int c = 0; c < 8; ++c) {
    short8 h, l;
    #pragma unroll
    for (int b = 0; b < 8; ++b) {
      float v = tile[k0 + c * 8 + b][j];
      ushort hh = f2b(v);
      h[b] = (short)hh;
      l[b] = (short)f2b(v - b2f(hh));
    }
    *(short8*)(WhT + obase + c * 8) = h;
    *(short8*)(WlT + obase + c * 8) = l;
  }
}

// ---------------- CSR build ----------------

__global__ void hist_kernel(const int* __restrict__ ei, int E, int* __restrict__ cnt) {
  int e = blockIdx.x * blockDim.x + threadIdx.x;
  if (e < E) atomicAdd(&cnt[ei[E + e]], 1);  // dst = ei[E+e]
}

// exclusive prefix sum of cnt[0..n-1] -> ofs[0..n], single block of 1024
__global__ void scan_kernel(const int* __restrict__ cnt, int* __restrict__ ofs, int n) {
  __shared__ int wsum[16];
  __shared__ int carry;
  int tid = threadIdx.x;
  int lane = tid & 63;
  int wid = tid >> 6;
  if (tid == 0) carry = 0;
  __syncthreads();
  for (int base = 0; base < n; base += 1024) {
    int i = base + tid;
    int v = (i < n) ? cnt[i] : 0;
    int x = v;
    #pragma unroll
    for (int d = 1; d < 64; d <<= 1) {
      int y = __shfl_up(x, d);
      if (lane >= d) x += y;
    }
    if (lane == 63) wsum[wid] = x;
    __syncthreads();
    if (wid == 0) {
      int s = (lane < 16) ? wsum[lane] : 0;
      #pragma unroll
      for (int d = 1; d < 16; d <<= 1) {
        int y = __shfl_up(s, d);
        if (lane >= d) s += y;
      }
      if (lane < 16) wsum[lane] = s;
    }
    __syncthreads();
    int waveoff = (wid > 0) ? wsum[wid - 1] : 0;
    int incl = x + waveoff;
    int total = wsum[15];
    int c = carry;
    if (i < n) ofs[i] = c + incl - v;
    __syncthreads();
    if (tid == 0) carry = c + total;
    __syncthreads();
  }
  if (tid == 0) ofs[n] = carry;
}

__global__ void scatter_kernel(const int* __restrict__ ei, int E,
                               const int* __restrict__ ofs, int* __restrict__ cur,
                               int* __restrict__ csr) {
  int e = blockIdx.x * blockDim.x + threadIdx.x;
  if (e < E) {
    int d = ei[E + e];
    int p = ofs[d] + atomicAdd(&cur[d], 1);
    csr[p] = ei[e];  // src
  }
}

// ---------------- CSR sum-aggregation, 4-edge groups ----------------

__global__ __launch_bounds__(256) void agg_kernel(
    const ushort* __restrict__ Xh, const int* __restrict__ csr,
    const int* __restrict__ ofs, ushort* __restrict__ Gh,
    ushort* __restrict__ Gl, int N) {
  int node = (blockIdx.x * blockDim.x + threadIdx.x) >> 6;
  int lane = threadIdx.x & 63;
  if (node >= N) return;
  int g = lane >> 4, q = lane & 15;
  int beg = ofs[node], end = ofs[node + 1];
  float a[8] = {};
  for (int p = beg + g; p < end; p += 4) {
    int s = csr[p];
    short8 v = *(const short8*)(Xh + (size_t)s * 128 + q * 8);
    #pragma unroll
    for (int b = 0; b < 8; ++b) a[b] += b2f((ushort)v[b]);
  }
  #pragma unroll
  for (int b = 0; b < 8; ++b) {
    a[b] += __shfl_xor(a[b], 16);
    a[b] += __shfl_xor(a[b], 32);
  }
  if (lane < 16) {
    short8 h, l;
    #pragma unroll
    for (int b = 0; b < 8; ++b) {
      ushort hh = f2b(a[b]);
      h[b] = (short)hh;
      l[b] = (short)f2b(a[b] - b2f(hh));
    }
    *(short8*)(Gh + (size_t)node * 128 + q * 8) = h;
    *(short8*)(Gl + (size_t)node * 128 + q * 8) = l;
  }
}

// ---------------- bf16x3 MFMA GEMM, LDS-staged (m97 pattern) ----------------
// 64-row tile/block, 512 threads = 8 waves, wave w owns cols [16w,16w+16).
// Stage 2S tiles of [64 rows][256 B] into LDS via global_load_lds(16B):
// linear LDS dest, XOR-swizzled global source (cb ^ (row&7)<<4); reads apply
// the same XOR -> conflict-free. One barrier; then ds_read_b128 + 24S MFMAs
// per rf-step. W from pre-split transposed arrays (16B loads).
// A frag (16x16x32): lane l -> row (l&15), k = (l>>4)*8 + b.
// D frag: col = l&15, row = (l>>4)*4 + reg   [validated rounds 2-5].

template <int S, bool RELU, bool BIAS>
__global__ __launch_bounds__(512, 2) void mgemm_kernel(
    const ushort* __restrict__ A1h, const ushort* __restrict__ A1l,
    const ushort* __restrict__ A2h, const ushort* __restrict__ A2l,
    const ushort* __restrict__ WhT, const ushort* __restrict__ WlT,
    const float* __restrict__ bias,
    ushort* __restrict__ Ch, ushort* __restrict__ Cl, int M) {
  __shared__ char lds[2 * S * 16384];   // 2S tiles of 16 KB (64 rows x 256 B)
  int t = threadIdx.x;
  int l = t & 63;
  int w = t >> 6;
  int j = (w << 4) + (l & 15);      // output column
  int krow0 = (l >> 4) * 8;         // k offset within 32-wide k-step
  int rowBase = blockIdx.x * 64;

  // ---- stage A tiles: 1024 chunks of 16B per tensor, 2 per thread ----
  const ushort* srcs[4] = {A1h, A1l, (S > 1) ? A2h : A1h, (S > 1) ? A2l : A1l};
  int ldsWaveBase0 = (t & ~63) * 16;             // uniform per wave, part 0
  #pragma unroll
  for (int q = 0; q < 2 * S; ++q) {
    const char* gsrc = (const char*)srcs[q];
    #pragma unroll
    for (int part = 0; part < 2; ++part) {
      int c = part * 512 + t;                    // chunk id 0..1023
      int r = c >> 4;                            // tile row
      int cb = (c & 15) << 4;                    // byte col within row
      int row = rowBase + r;
      if (row >= M) row = M - 1;
      int sb = cb ^ ((r & 7) << 4);              // inverse-swizzled source col
      gload_lds16(gsrc + (size_t)row * 256 + sb,
                  &lds[q * 16384 + part * 8192 + ldsWaveBase0]);
    }
  }

  // ---- W fragments from pre-split transposed W (independent of staging) ----
  short8 wh[S][4], wl[S][4];
  #pragma unroll
  for (int s = 0; s < S; ++s) {
    #pragma unroll
    for (int ks = 0; ks < 4; ++ks) {
      size_t wb = (size_t)s * 16384 + (size_t)j * 128 + ks * 32 + krow0;
      wh[s][ks] = *(const short8*)(WhT + wb);
      wl[s][ks] = *(const short8*)(WlT + wb);
    }
  }

  __syncthreads();   // drains vmcnt (global_load_lds) per __syncthreads semantics

  // ---- compute: ds_read_b128 (swizzled) + 3 MFMAs per (rf,s,ks) ----
  f32x4 acc[4];
  #pragma unroll
  for (int i = 0; i < 4; ++i) acc[i] = (f32x4){0.f, 0.f, 0.f, 0.f};

  #pragma unroll
  for (int rf = 0; rf < 4; ++rf) {
    int r = rf * 16 + (l & 15);
    int sw = (r & 7) << 4;
    int rb = r * 256;
    #pragma unroll
    for (int s = 0; s < S; ++s) {
      #pragma unroll
      for (int ks = 0; ks < 4; ++ks) {
        int off = rb + ((ks * 64 + (l >> 4) * 16) ^ sw);
        short8 ah = *(const short8*)&lds[(s * 2 + 0) * 16384 + off];
        short8 al = *(const short8*)&lds[(s * 2 + 1) * 16384 + off];
        acc[rf] = __builtin_amdgcn_mfma_f32_16x16x32_bf16(al, wh[s][ks], acc[rf], 0, 0, 0);
        acc[rf] = __builtin_amdgcn_mfma_f32_16x16x32_bf16(ah, wl[s][ks], acc[rf], 0, 0, 0);
        acc[rf] = __builtin_amdgcn_mfma_f32_16x16x32_bf16(ah, wh[s][ks], acc[rf], 0, 0, 0);
      }
    }
  }

  float bj = BIAS ? bias[j] : 0.f;
  #pragma unroll
  for (int rf = 0; rf < 4; ++rf) {
    int rbase = rowBase + rf * 16 + (l >> 4) * 4;
    #pragma unroll
    for (int r = 0; r < 4; ++r) {
      int row = rbase + r;
      if (row < M) {
        float v = acc[rf][r];
        if (BIAS) v += bj;
        if (RELU) v = fmaxf(v, 0.f);
        ushort h = f2b(v);
        Ch[(size_t)row * 128 + j] = h;
        Cl[(size_t)row * 128 + j] = f2b(v - b2f(h));
      }
    }
  }
}

// ---------------- per-node dots: s_src = ht.a_src, s_dst = ht.a_dst ----------------

__global__ __launch_bounds__(256) void dots_kernel(
    const ushort* __restrict__ HTh, const ushort* __restrict__ HTl,
    const float* __restrict__ a_src, const float* __restrict__ a_dst,
    float* __restrict__ ssrc, float* __restrict__ sdst, int N) {
  int n = (blockIdx.x * blockDim.x + threadIdx.x) >> 6;
  int lane = threadIdx.x & 63;
  if (n >= N) return;
  uint uh = ((const uint*)(HTh + (size_t)n * 128))[lane];
  uint ul = ((const uint*)(HTl + (size_t)n * 128))[lane];
  float h0 = b2f((ushort)(uh & 0xffff)) + b2f((ushort)(ul & 0xffff));
  float h1 = b2f((ushort)(uh >> 16)) + b2f((ushort)(ul >> 16));
  float vs = h0 * a_src[2 * lane] + h1 * a_src[2 * lane + 1];
  float vd = h0 * a_dst[2 * lane] + h1 * a_dst[2 * lane + 1];
  #pragma unroll
  for (int d = 32; d > 0; d >>= 1) {
    vs += __shfl_xor(vs, d);
    vd += __shfl_xor(vd, d);
  }
  if (lane == 0) { ssrc[n] = vs; sdst[n] = vd; }
}

// ---------------- fused attention: online segment softmax + weighted PV ----------------

__global__ __launch_bounds__(256) void attn_kernel(
    const ushort* __restrict__ HTh, const int* __restrict__ csr,
    const int* __restrict__ ofs, const float* __restrict__ ssrc,
    const float* __restrict__ sdst, float* __restrict__ outh, int N) {
  int n = (blockIdx.x * blockDim.x + threadIdx.x) >> 6;
  int lane = threadIdx.x & 63;
  if (n >= N) return;
  int beg = ofs[n], end = ofs[n + 1];
  float sd = sdst[n];

  // phase 1: online max + denom in a single edge pass
  float m = -3.4e38f, ssum = 0.f;
  for (int p = beg + lane; p < end; p += 64) {
    float e = ssrc[csr[p]] + sd;
    e = (e >= 0.f) ? e : 0.2f * e;
    float nm = fmaxf(m, e);
    ssum = ssum * __expf(m - nm) + __expf(e - nm);
    m = nm;
  }
  #pragma unroll
  for (int d = 32; d > 0; d >>= 1) {
    float om = __shfl_xor(m, d);
    float os = __shfl_xor(ssum, d);
    float nm = fmaxf(m, om);
    ssum = ssum * __expf(m - nm) + os * __expf(om - nm);
    m = nm;
  }
  float inv = 1.0f / (ssum + 1e-16f);

  // phase 2: weighted PV, 4-edge groups with 16B loads
  int g = lane >> 4, q = lane & 15;
  float a[8] = {};
  for (int p = beg + g; p < end; p += 4) {
    int s = csr[p];
    float e = ssrc[s] + sd;
    e = (e >= 0.f) ? e : 0.2f * e;
    float wgt = __expf(e - m) * inv;
    short8 v = *(const short8*)(HTh + (size_t)s * 128 + q * 8);
    #pragma unroll
    for (int b = 0; b < 8; ++b) a[b] += wgt * b2f((ushort)v[b]);
  }
  #pragma unroll
  for (int b = 0; b < 8; ++b) {
    a[b] += __shfl_xor(a[b], 16);
    a[b] += __shfl_xor(a[b], 32);
  }
  if (lane < 16) {
    float4 o0 = {a[0], a[1], a[2], a[3]};
    float4 o1 = {a[4], a[5], a[6], a[7]};
    *(float4*)(outh + (size_t)n * 128 + q * 8) = o0;
    *(float4*)(outh + (size_t)n * 128 + q * 8 + 4) = o1;
  }
}

// ---------------- final FC: out = out_h @ Wfc + bfc  (128 -> 2) ----------------

__global__ __launch_bounds__(256) void fc_kernel(
    const float* __restrict__ H, const float* __restrict__ Wfc,
    const float* __restrict__ bfc, float* __restrict__ out, int N) {
  int n = (blockIdx.x * blockDim.x + threadIdx.x) >> 6;
  int lane = threadIdx.x & 63;
  if (n >= N) return;
  float h0 = H[(size_t)n * 128 + lane];
  float h1 = H[(size_t)n * 128 + 64 + lane];
  float o0 = h0 * Wfc[lane * 2 + 0] + h1 * Wfc[(lane + 64) * 2 + 0];
  float o1 = h0 * Wfc[lane * 2 + 1] + h1 * Wfc[(lane + 64) * 2 + 1];
  #pragma unroll
  for (int d = 32; d > 0; d >>= 1) {
    o0 += __shfl_xor(o0, d);
    o1 += __shfl_xor(o1, d);
  }
  if (lane == 0) {
    out[(size_t)n * 2 + 0] = o0 + bfc[0];
    out[(size_t)n * 2 + 1] = o1 + bfc[1];
  }
}

// ---------------- launch ----------------

static inline size_t align_up(size_t x, size_t a) { return (x + a - 1) & ~(a - 1); }

extern "C" void kernel_launch(void* const* d_in, const int* in_sizes, int n_in,
                              void* d_out, int out_size, void* d_ws, size_t ws_size,
                              hipStream_t stream) {
  const float* x     = (const float*)d_in[0];
  const int*   ei    = (const int*)d_in[1];
  const float* W1r   = (const float*)d_in[2];
  const float* W1n   = (const float*)d_in[3];
  const float* b1    = (const float*)d_in[4];
  const float* W2r   = (const float*)d_in[5];
  const float* W2n   = (const float*)d_in[6];
  const float* b2    = (const float*)d_in[7];
  const float* Wa    = (const float*)d_in[8];
  const float* a_src = (const float*)d_in[9];
  const float* a_dst = (const float*)d_in[10];
  const float* Wfc   = (const float*)d_in[11];
  const float* bfc   = (const float*)d_in[12];

  const int N = in_sizes[0] / 128;   // 50000
  const int E = in_sizes[1] / 2;     // 800000

  // workspace carve-up
  char* ws = (char*)d_ws;
  size_t off = 0;
  auto take = [&](size_t bytes) {
    char* p = ws + off;
    off = align_up(off + bytes, 256);
    return p;
  };
  const size_t NB = (size_t)N * 128 * 2;  // one bf16 node tensor (12.8 MB)
  int*    ofs  = (int*)take((size_t)(N + 1) * 4);
  int*    cnt  = (int*)take((size_t)N * 4);
  int*    cur  = (int*)take((size_t)N * 4);
  int*    csr  = (int*)take((size_t)E * 4);
  float*  ssrc = (float*)take((size_t)N * 4);
  float*  sdst = (float*)take((size_t)N * 4);
  ushort* whT  = (ushort*)take((size_t)5 * 16384 * 2);  // pre-split W hi
  ushort* wlT  = (ushort*)take((size_t)5 * 16384 * 2);  // pre-split W lo
  ushort* bA   = (ushort*)take(NB);   // x_hi  -> h2_hi
  ushort* bB   = (ushort*)take(NB);   // x_lo  -> h2_lo
  ushort* bC   = (ushort*)take(NB);   // g_hi  -> ht_hi
  ushort* bD   = (ushort*)take(NB);   // g_lo  -> ht_lo
  ushort* bE   = (ushort*)take(NB);   // h1_hi -.
  ushort* bF   = (ushort*)take(NB);   // h1_lo  }-> outh (fp32, spans E+F)
  float*  outh = (float*)bE;

  hipMemsetAsync(cnt, 0, (size_t)N * 4, stream);
  hipMemsetAsync(cur, 0, (size_t)N * 4, stream);

  const int edgeBlocks = (E + 255) / 256;
  const int nodeBlocks = (N + 3) / 4;     // 4 waves per 256-thread block
  const int gemmBlocks = (N + 63) / 64;   // 64-row LDS-staged tiles
  const int splitBlocks = (N * 128 / 8 + 255) / 256;

  // W pre-split (mats: 0=W1r 1=W1n 2=W2r 3=W2n 4=Wa), x split, CSR build
  wsplit_kernel<<<5, 256, 0, stream>>>(W1r, W1n, W2r, W2n, Wa, whT, wlT);
  split_kernel<<<splitBlocks, 256, 0, stream>>>(x, bA, bB, N * 128);
  hist_kernel<<<edgeBlocks, 256, 0, stream>>>(ei, E, cnt);
  scan_kernel<<<1, 1024, 0, stream>>>(cnt, ofs, N);
  scatter_kernel<<<edgeBlocks, 256, 0, stream>>>(ei, E, ofs, cur, csr);

  // layer 1: agg1 = sum(x_hi); h1 = relu(x@W1r + agg1@W1n + b1)
  agg_kernel<<<nodeBlocks, 256, 0, stream>>>(bA, csr, ofs, bC, bD, N);
  mgemm_kernel<2, true, true><<<gemmBlocks, 512, 0, stream>>>(
      bA, bB, bC, bD, whT, wlT, b1, bE, bF, N);                    // h1 -> E,F

  // layer 2: agg2 = sum(h1_hi); h2 = relu(h1@W2r + agg2@W2n + b2)
  agg_kernel<<<nodeBlocks, 256, 0, stream>>>(bE, csr, ofs, bC, bD, N);
  mgemm_kernel<2, true, true><<<gemmBlocks, 512, 0, stream>>>(
      bE, bF, bC, bD, whT + 2 * 16384, wlT + 2 * 16384, b2, bA, bB, N);  // h2 -> A,B

  // attention transform: ht = h2@Wa -> C,D
  mgemm_kernel<1, false, false><<<gemmBlocks, 512, 0, stream>>>(
      bA, bB, nullptr, nullptr, whT + 4 * 16384, wlT + 4 * 16384,
      nullptr, bC, bD, N);
  dots_kernel<<<nodeBlocks, 256, 0, stream>>>(bC, bD, a_src, a_dst, ssrc, sdst, N);
  attn_kernel<<<nodeBlocks, 256, 0, stream>>>(bC, csr, ofs, ssrc, sdst, outh, N);

  // output FC
  fc_kernel<<<nodeBlocks, 256, 0, stream>>>(outh, Wfc, bfc, (float*)d_out, N);
}

// Round 7
// 281.551 us; speedup vs baseline: 1.5996x; 1.2556x over previous
//
#include <hip/hip_runtime.h>
#include <cstddef>
#include <cstdint>

// ---------------------------------------------------------------------------
// GraphNeuralNetworkRiskManager: 2x GraphConv (sum-agg) + GAT attention + FC
// N=50000 nodes, E=800000 edges, F_IN=HID=128, F_OUT=2.
//
// Round 7: CSR build replaced (round-6 diagnosis: scatter_kernel wrote 55 MB
// for a 3.2 MB array -- one HBM line per random 4B store across XCDs):
//   bhist (LDS hist -> 128 atomics/block) -> bscan (128-wide) ->
//   bscatter (LDS counting-sort per chunk, coalesced pair runs into bucket
//   regions) -> csrbuild (one block per 512-node bucket: LDS hist+scan,
//   block-private csr writes -> line-dense, single-XCD).
// GEMMs: bf16x3 MFMA, LDS-staged via global_load_lds (m97 pattern), XOR
// swizzle on global source + LDS read. Node tensors bf16 hi+lo pairs.
// ---------------------------------------------------------------------------

typedef __attribute__((ext_vector_type(8))) short short8;
typedef __attribute__((ext_vector_type(4))) float f32x4;

#define NBUK 128
#define BSH  9          // bucket = dst >> 9 (512 nodes per bucket)
#define CHUNK 1568      // edges per bscatter block

__device__ __forceinline__ ushort f2b(float f) {       // fp32 -> bf16 bits, RNE
  uint32_t u = __float_as_uint(f);
  u += 0x7fffu + ((u >> 16) & 1u);
  return (ushort)(u >> 16);
}
__device__ __forceinline__ float b2f(ushort h) {       // bf16 bits -> fp32
  return __uint_as_float(((uint32_t)h) << 16);
}

__device__ __forceinline__ void gload_lds16(const void* g, void* l) {
  __builtin_amdgcn_global_load_lds(
      (const __attribute__((address_space(1))) void*)g,
      (__attribute__((address_space(3))) void*)l, 16, 0, 0);
}

// ---------------- fp32 -> (hi, lo) bf16 split of x ----------------

__global__ __launch_bounds__(256) void split_kernel(
    const float* __restrict__ in, ushort* __restrict__ hi,
    ushort* __restrict__ lo, int n) {
  int i = (blockIdx.x * blockDim.x + threadIdx.x) * 8;
  if (i >= n) return;
  float4 v0 = *(const float4*)(in + i);
  float4 v1 = *(const float4*)(in + i + 4);
  float v[8] = {v0.x, v0.y, v0.z, v0.w, v1.x, v1.y, v1.z, v1.w};
  short8 h, l;
  #pragma unroll
  for (int b = 0; b < 8; ++b) {
    ushort hh = f2b(v[b]);
    h[b] = (short)hh;
    l[b] = (short)f2b(v[b] - b2f(hh));
  }
  *(short8*)(hi + i) = h;
  *(short8*)(lo + i) = l;
}

// ---------------- W split+transpose: W[k][j] fp32 -> WhT/WlT[m][j][k] bf16 ----------------

__global__ __launch_bounds__(256) void wsplit_kernel(
    const float* __restrict__ W0, const float* __restrict__ W1,
    const float* __restrict__ W2, const float* __restrict__ W3,
    const float* __restrict__ W4,
    ushort* __restrict__ WhT, ushort* __restrict__ WlT) {
  __shared__ float tile[128][128];
  int m = blockIdx.x;
  const float* W = (m == 0) ? W0 : (m == 1) ? W1 : (m == 2) ? W2 : (m == 3) ? W3 : W4;
  int t = threadIdx.x;
  #pragma unroll
  for (int i = 0; i < 64; ++i) {
    int idx = i * 256 + t;                 // coalesced read
    tile[idx >> 7][idx & 127] = W[idx];
  }
  __syncthreads();
  int j = t >> 1, k0 = (t & 1) * 64;
  size_t obase = (size_t)m * 16384 + (size_t)j * 128 + k0;
  #pragma unroll
  for (int c = 0; c < 8; ++c) {
    short8 h, l;
    #pragma unroll
    for (int b = 0; b < 8; ++b) {
      float v = tile[k0 + c * 8 + b][j];
      ushort hh = f2b(v);
      h[b] = (short)hh;
      l[b] = (short)f2b(v - b2f(hh));
    }
    *(short8*)(WhT + obase + c * 8) = h;
    *(short8*)(WlT + obase + c * 8) = l;
  }
}

// ---------------- CSR build, bucketed ----------------

// K1: per-block LDS bucket histogram, 128 global atomics per block
__global__ __launch_bounds__(256) void bhist_kernel(
    const int* __restrict__ ei, int E, int* __restrict__ bcnt) {
  __shared__ int lh[NBUK];
  int t = threadIdx.x;
  if (t < NBUK) lh[t] = 0;
  __syncthreads();
  int base = blockIdx.x * CHUNK;
  int lim = base + CHUNK; if (lim > E) lim = E;
  for (int i = base + t; i < lim; i += 256) atomicAdd(&lh[ei[E + i] >> BSH], 1);
  __syncthreads();
  if (t < NBUK && lh[t]) atomicAdd(&bcnt[t], lh[t]);
}

// K2: exclusive scan of 128 bucket counts -> bbase[0..128], gtail init
__global__ __launch_bounds__(256) void bscan_kernel(
    const int* __restrict__ bcnt, int* __restrict__ bbase,
    int* __restrict__ gtail) {
  __shared__ int sA[NBUK], sB[NBUK];
  int t = threadIdx.x;
  if (t < NBUK) sA[t] = bcnt[t];
  __syncthreads();
  int *s = sA, *d = sB;
  for (int st = 1; st < NBUK; st <<= 1) {
    if (t < NBUK) d[t] = s[t] + ((t >= st) ? s[t - st] : 0);
    __syncthreads();
    int* tmp = s; s = d; d = tmp;
  }
  if (t < NBUK) {
    int exc = (t == 0) ? 0 : s[t - 1];
    bbase[t] = exc;
    gtail[t] = exc;
  }
  if (t == 0) bbase[NBUK] = s[NBUK - 1];
}

// K3: per-block LDS counting sort of a chunk -> coalesced runs into buckets
__global__ __launch_bounds__(256) void bscatter_kernel(
    const int* __restrict__ ei, int E, int* __restrict__ gtail,
    uint2* __restrict__ pair) {
  __shared__ int lh[NBUK], sB[NBUK], lofs[NBUK], lcur[NBUK], gbase[NBUK];
  __shared__ uint2 buf[CHUNK];
  int t = threadIdx.x;
  if (t < NBUK) lh[t] = 0;
  __syncthreads();
  int base = blockIdx.x * CHUNK;
  int lim = base + CHUNK; if (lim > E) lim = E;
  for (int i = base + t; i < lim; i += 256) atomicAdd(&lh[ei[E + i] >> BSH], 1);
  __syncthreads();
  int *s = lh, *d = sB;
  for (int st = 1; st < NBUK; st <<= 1) {
    if (t < NBUK) d[t] = s[t] + ((t >= st) ? s[t - st] : 0);
    __syncthreads();
    int* tmp = s; s = d; d = tmp;
  }
  if (t < NBUK) {
    lofs[t] = (t == 0) ? 0 : s[t - 1];
    lcur[t] = lofs[t];
  }
  __syncthreads();
  // local bucket-sort into buf
  for (int i = base + t; i < lim; i += 256) {
    int srcv = ei[i], dstv = ei[E + i];
    int p = atomicAdd(&lcur[dstv >> BSH], 1);
    buf[p] = make_uint2((unsigned)srcv, (unsigned)dstv);
  }
  __syncthreads();
  // reserve global space per bucket
  if (t < NBUK) {
    int c = s[t] - lofs[t];
    gbase[t] = c ? atomicAdd(&gtail[t], c) : 0;
  }
  __syncthreads();
  int n = lim - base;
  for (int i = t; i < n; i += 256) {
    uint2 pr = buf[i];
    int b = ((int)pr.y) >> BSH;
    pair[gbase[b] + (i - lofs[b])] = pr;
  }
}

// K4: one block per bucket: LDS hist+scan over 512 nodes, write ofs + csr
__global__ __launch_bounds__(256) void csrbuild_kernel(
    const uint2* __restrict__ pair, const int* __restrict__ bbase,
    int* __restrict__ ofs, int* __restrict__ csr, int N, int E) {
  __shared__ int hA[512], hB[512];
  int b = blockIdx.x, t = threadIdx.x;
  int base = bbase[b], cnt = bbase[b + 1] - base;
  int node0 = b << BSH;
  int nn = N - node0; if (nn > 512) nn = 512;
  hA[t] = 0; hA[t + 256] = 0;
  __syncthreads();
  for (int i = t; i < cnt; i += 256)
    atomicAdd(&hA[(int)pair[base + i].y - node0], 1);
  __syncthreads();
  int *s = hA, *d = hB;
  for (int st = 1; st < 512; st <<= 1) {
    #pragma unroll
    for (int k = 0; k < 2; ++k) {
      int i = t + k * 256;
      d[i] = s[i] + ((i >= st) ? s[i - st] : 0);
    }
    __syncthreads();
    int* tmp = s; s = d; d = tmp;
  }
  // s = inclusive scan; write ofs (coalesced)
  #pragma unroll
  for (int k = 0; k < 2; ++k) {
    int i = t + k * 256;
    if (i < nn) ofs[node0 + i] = base + (i == 0 ? 0 : s[i - 1]);
  }
  if (t == 0 && node0 + nn >= N) ofs[N] = E;
  // cur = exclusive scan (reuse the non-result buffer d)
  #pragma unroll
  for (int k = 0; k < 2; ++k) {
    int i = t + k * 256;
    d[i] = (i == 0 ? 0 : s[i - 1]);
  }
  __syncthreads();
  for (int i = t; i < cnt; i += 256) {
    uint2 pr = pair[base + i];
    int p = atomicAdd(&d[(int)pr.y - node0], 1);
    csr[base + p] = (int)pr.x;
  }
}

// ---------------- CSR sum-aggregation, 4-edge groups ----------------

__global__ __launch_bounds__(256) void agg_kernel(
    const ushort* __restrict__ Xh, const int* __restrict__ csr,
    const int* __restrict__ ofs, ushort* __restrict__ Gh,
    ushort* __restrict__ Gl, int N) {
  int node = (blockIdx.x * blockDim.x + threadIdx.x) >> 6;
  int lane = threadIdx.x & 63;
  if (node >= N) return;
  int g = lane >> 4, q = lane & 15;
  int beg = ofs[node], end = ofs[node + 1];
  float a[8] = {};
  for (int p = beg + g; p < end; p += 4) {
    int s = csr[p];
    short8 v = *(const short8*)(Xh + (size_t)s * 128 + q * 8);
    #pragma unroll
    for (int b = 0; b < 8; ++b) a[b] += b2f((ushort)v[b]);
  }
  #pragma unroll
  for (int b = 0; b < 8; ++b) {
    a[b] += __shfl_xor(a[b], 16);
    a[b] += __shfl_xor(a[b], 32);
  }
  if (lane < 16) {
    short8 h, l;
    #pragma unroll
    for (int b = 0; b < 8; ++b) {
      ushort hh = f2b(a[b]);
      h[b] = (short)hh;
      l[b] = (short)f2b(a[b] - b2f(hh));
    }
    *(short8*)(Gh + (size_t)node * 128 + q * 8) = h;
    *(short8*)(Gl + (size_t)node * 128 + q * 8) = l;
  }
}

// ---------------- bf16x3 MFMA GEMM, LDS-staged (m97 pattern) ----------------

template <int S, bool RELU, bool BIAS>
__global__ __launch_bounds__(512, 2) void mgemm_kernel(
    const ushort* __restrict__ A1h, const ushort* __restrict__ A1l,
    const ushort* __restrict__ A2h, const ushort* __restrict__ A2l,
    const ushort* __restrict__ WhT, const ushort* __restrict__ WlT,
    const float* __restrict__ bias,
    ushort* __restrict__ Ch, ushort* __restrict__ Cl, int M) {
  __shared__ char lds[2 * S * 16384];   // 2S tiles of 16 KB (64 rows x 256 B)
  int t = threadIdx.x;
  int l = t & 63;
  int w = t >> 6;
  int j = (w << 4) + (l & 15);      // output column
  int krow0 = (l >> 4) * 8;         // k offset within 32-wide k-step
  int rowBase = blockIdx.x * 64;

  // ---- stage A tiles: 1024 chunks of 16B per tensor, 2 per thread ----
  const ushort* srcs[4] = {A1h, A1l, (S > 1) ? A2h : A1h, (S > 1) ? A2l : A1l};
  int ldsWaveBase0 = (t & ~63) * 16;             // uniform per wave, part 0
  #pragma unroll
  for (int q = 0; q < 2 * S; ++q) {
    const char* gsrc = (const char*)srcs[q];
    #pragma unroll
    for (int part = 0; part < 2; ++part) {
      int c = part * 512 + t;                    // chunk id 0..1023
      int r = c >> 4;                            // tile row
      int cb = (c & 15) << 4;                    // byte col within row
      int row = rowBase + r;
      if (row >= M) row = M - 1;
      int sb = cb ^ ((r & 7) << 4);              // inverse-swizzled source col
      gload_lds16(gsrc + (size_t)row * 256 + sb,
                  &lds[q * 16384 + part * 8192 + ldsWaveBase0]);
    }
  }

  // ---- W fragments from pre-split transposed W ----
  short8 wh[S][4], wl[S][4];
  #pragma unroll
  for (int s = 0; s < S; ++s) {
    #pragma unroll
    for (int ks = 0; ks < 4; ++ks) {
      size_t wb = (size_t)s * 16384 + (size_t)j * 128 + ks * 32 + krow0;
      wh[s][ks] = *(const short8*)(WhT + wb);
      wl[s][ks] = *(const short8*)(WlT + wb);
    }
  }

  __syncthreads();   // drains vmcnt (global_load_lds)

  f32x4 acc[4];
  #pragma unroll
  for (int i = 0; i < 4; ++i) acc[i] = (f32x4){0.f, 0.f, 0.f, 0.f};

  #pragma unroll
  for (int rf = 0; rf < 4; ++rf) {
    int r = rf * 16 + (l & 15);
    int sw = (r & 7) << 4;
    int rb = r * 256;
    #pragma unroll
    for (int s = 0; s < S; ++s) {
      #pragma unroll
      for (int ks = 0; ks < 4; ++ks) {
        int off = rb + ((ks * 64 + (l >> 4) * 16) ^ sw);
        short8 ah = *(const short8*)&lds[(s * 2 + 0) * 16384 + off];
        short8 al = *(const short8*)&lds[(s * 2 + 1) * 16384 + off];
        acc[rf] = __builtin_amdgcn_mfma_f32_16x16x32_bf16(al, wh[s][ks], acc[rf], 0, 0, 0);
        acc[rf] = __builtin_amdgcn_mfma_f32_16x16x32_bf16(ah, wl[s][ks], acc[rf], 0, 0, 0);
        acc[rf] = __builtin_amdgcn_mfma_f32_16x16x32_bf16(ah, wh[s][ks], acc[rf], 0, 0, 0);
      }
    }
  }

  float bj = BIAS ? bias[j] : 0.f;
  #pragma unroll
  for (int rf = 0; rf < 4; ++rf) {
    int rbase = rowBase + rf * 16 + (l >> 4) * 4;
    #pragma unroll
    for (int r = 0; r < 4; ++r) {
      int row = rbase + r;
      if (row < M) {
        float v = acc[rf][r];
        if (BIAS) v += bj;
        if (RELU) v = fmaxf(v, 0.f);
        ushort h = f2b(v);
        Ch[(size_t)row * 128 + j] = h;
        Cl[(size_t)row * 128 + j] = f2b(v - b2f(h));
      }
    }
  }
}

// ---------------- per-node dots: s_src = ht.a_src, s_dst = ht.a_dst ----------------

__global__ __launch_bounds__(256) void dots_kernel(
    const ushort* __restrict__ HTh, const ushort* __restrict__ HTl,
    const float* __restrict__ a_src, const float* __restrict__ a_dst,
    float* __restrict__ ssrc, float* __restrict__ sdst, int N) {
  int n = (blockIdx.x * blockDim.x + threadIdx.x) >> 6;
  int lane = threadIdx.x & 63;
  if (n >= N) return;
  uint uh = ((const uint*)(HTh + (size_t)n * 128))[lane];
  uint ul = ((const uint*)(HTl + (size_t)n * 128))[lane];
  float h0 = b2f((ushort)(uh & 0xffff)) + b2f((ushort)(ul & 0xffff));
  float h1 = b2f((ushort)(uh >> 16)) + b2f((ushort)(ul >> 16));
  float vs = h0 * a_src[2 * lane] + h1 * a_src[2 * lane + 1];
  float vd = h0 * a_dst[2 * lane] + h1 * a_dst[2 * lane + 1];
  #pragma unroll
  for (int d = 32; d > 0; d >>= 1) {
    vs += __shfl_xor(vs, d);
    vd += __shfl_xor(vd, d);
  }
  if (lane == 0) { ssrc[n] = vs; sdst[n] = vd; }
}

// ---------------- fused attention: online segment softmax + weighted PV ----------------

__global__ __launch_bounds__(256) void attn_kernel(
    const ushort* __restrict__ HTh, const int* __restrict__ csr,
    const int* __restrict__ ofs, const float* __restrict__ ssrc,
    const float* __restrict__ sdst, float* __restrict__ outh, int N) {
  int n = (blockIdx.x * blockDim.x + threadIdx.x) >> 6;
  int lane = threadIdx.x & 63;
  if (n >= N) return;
  int beg = ofs[n], end = ofs[n + 1];
  float sd = sdst[n];

  // phase 1: online max + denom in a single edge pass
  float m = -3.4e38f, ssum = 0.f;
  for (int p = beg + lane; p < end; p += 64) {
    float e = ssrc[csr[p]] + sd;
    e = (e >= 0.f) ? e : 0.2f * e;
    float nm = fmaxf(m, e);
    ssum = ssum * __expf(m - nm) + __expf(e - nm);
    m = nm;
  }
  #pragma unroll
  for (int d = 32; d > 0; d >>= 1) {
    float om = __shfl_xor(m, d);
    float os = __shfl_xor(ssum, d);
    float nm = fmaxf(m, om);
    ssum = ssum * __expf(m - nm) + os * __expf(om - nm);
    m = nm;
  }
  float inv = 1.0f / (ssum + 1e-16f);

  // phase 2: weighted PV, 4-edge groups with 16B loads
  int g = lane >> 4, q = lane & 15;
  float a[8] = {};
  for (int p = beg + g; p < end; p += 4) {
    int s = csr[p];
    float e = ssrc[s] + sd;
    e = (e >= 0.f) ? e : 0.2f * e;
    float wgt = __expf(e - m) * inv;
    short8 v = *(const short8*)(HTh + (size_t)s * 128 + q * 8);
    #pragma unroll
    for (int b = 0; b < 8; ++b) a[b] += wgt * b2f((ushort)v[b]);
  }
  #pragma unroll
  for (int b = 0; b < 8; ++b) {
    a[b] += __shfl_xor(a[b], 16);
    a[b] += __shfl_xor(a[b], 32);
  }
  if (lane < 16) {
    float4 o0 = {a[0], a[1], a[2], a[3]};
    float4 o1 = {a[4], a[5], a[6], a[7]};
    *(float4*)(outh + (size_t)n * 128 + q * 8) = o0;
    *(float4*)(outh + (size_t)n * 128 + q * 8 + 4) = o1;
  }
}

// ---------------- final FC: out = out_h @ Wfc + bfc  (128 -> 2) ----------------

__global__ __launch_bounds__(256) void fc_kernel(
    const float* __restrict__ H, const float* __restrict__ Wfc,
    const float* __restrict__ bfc, float* __restrict__ out, int N) {
  int n = (blockIdx.x * blockDim.x + threadIdx.x) >> 6;
  int lane = threadIdx.x & 63;
  if (n >= N) return;
  float h0 = H[(size_t)n * 128 + lane];
  float h1 = H[(size_t)n * 128 + 64 + lane];
  float o0 = h0 * Wfc[lane * 2 + 0] + h1 * Wfc[(lane + 64) * 2 + 0];
  float o1 = h0 * Wfc[lane * 2 + 1] + h1 * Wfc[(lane + 64) * 2 + 1];
  #pragma unroll
  for (int d = 32; d > 0; d >>= 1) {
    o0 += __shfl_xor(o0, d);
    o1 += __shfl_xor(o1, d);
  }
  if (lane == 0) {
    out[(size_t)n * 2 + 0] = o0 + bfc[0];
    out[(size_t)n * 2 + 1] = o1 + bfc[1];
  }
}

// ---------------- launch ----------------

static inline size_t align_up(size_t x, size_t a) { return (x + a - 1) & ~(a - 1); }

extern "C" void kernel_launch(void* const* d_in, const int* in_sizes, int n_in,
                              void* d_out, int out_size, void* d_ws, size_t ws_size,
                              hipStream_t stream) {
  const float* x     = (const float*)d_in[0];
  const int*   ei    = (const int*)d_in[1];
  const float* W1r   = (const float*)d_in[2];
  const float* W1n   = (const float*)d_in[3];
  const float* b1    = (const float*)d_in[4];
  const float* W2r   = (const float*)d_in[5];
  const float* W2n   = (const float*)d_in[6];
  const float* b2    = (const float*)d_in[7];
  const float* Wa    = (const float*)d_in[8];
  const float* a_src = (const float*)d_in[9];
  const float* a_dst = (const float*)d_in[10];
  const float* Wfc   = (const float*)d_in[11];
  const float* bfc   = (const float*)d_in[12];

  const int N = in_sizes[0] / 128;   // 50000
  const int E = in_sizes[1] / 2;     // 800000

  // workspace carve-up
  char* ws = (char*)d_ws;
  size_t off = 0;
  auto take = [&](size_t bytes) {
    char* p = ws + off;
    off = align_up(off + bytes, 256);
    return p;
  };
  const size_t NB = (size_t)N * 128 * 2;  // one bf16 node tensor (12.8 MB)
  int*    ofs   = (int*)take((size_t)(N + 1) * 4);
  int*    csr   = (int*)take((size_t)E * 4);
  int*    bcnt  = (int*)take(NBUK * 4);
  int*    bbase = (int*)take((NBUK + 1) * 4);
  int*    gtail = (int*)take(NBUK * 4);
  uint2*  pair  = (uint2*)take((size_t)E * 8);
  float*  ssrc  = (float*)take((size_t)N * 4);
  float*  sdst  = (float*)take((size_t)N * 4);
  ushort* whT   = (ushort*)take((size_t)5 * 16384 * 2);  // pre-split W hi
  ushort* wlT   = (ushort*)take((size_t)5 * 16384 * 2);  // pre-split W lo
  ushort* bA    = (ushort*)take(NB);   // x_hi  -> h2_hi
  ushort* bB    = (ushort*)take(NB);   // x_lo  -> h2_lo
  ushort* bC    = (ushort*)take(NB);   // g_hi  -> ht_hi
  ushort* bD    = (ushort*)take(NB);   // g_lo  -> ht_lo
  ushort* bE    = (ushort*)take(NB);   // h1_hi -.
  ushort* bF    = (ushort*)take(NB);   // h1_lo  }-> outh (fp32, spans E+F)
  float*  outh  = (float*)bE;

  hipMemsetAsync(bcnt, 0, NBUK * 4, stream);

  const int nodeBlocks = (N + 3) / 4;     // 4 waves per 256-thread block
  const int gemmBlocks = (N + 63) / 64;   // 64-row LDS-staged tiles
  const int splitBlocks = (N * 128 / 8 + 255) / 256;
  const int chunkBlocks = (E + CHUNK - 1) / CHUNK;
  const int bukBlocks   = (N + 511) / 512;

  // W pre-split (mats: 0=W1r 1=W1n 2=W2r 3=W2n 4=Wa), x split, CSR build
  wsplit_kernel<<<5, 256, 0, stream>>>(W1r, W1n, W2r, W2n, Wa, whT, wlT);
  split_kernel<<<splitBlocks, 256, 0, stream>>>(x, bA, bB, N * 128);
  bhist_kernel<<<chunkBlocks, 256, 0, stream>>>(ei, E, bcnt);
  bscan_kernel<<<1, 256, 0, stream>>>(bcnt, bbase, gtail);
  bscatter_kernel<<<chunkBlocks, 256, 0, stream>>>(ei, E, gtail, pair);
  csrbuild_kernel<<<bukBlocks, 256, 0, stream>>>(pair, bbase, ofs, csr, N, E);

  // layer 1: agg1 = sum(x_hi); h1 = relu(x@W1r + agg1@W1n + b1)
  agg_kernel<<<nodeBlocks, 256, 0, stream>>>(bA, csr, ofs, bC, bD, N);
  mgemm_kernel<2, true, true><<<gemmBlocks, 512, 0, stream>>>(
      bA, bB, bC, bD, whT, wlT, b1, bE, bF, N);                    // h1 -> E,F

  // layer 2: agg2 = sum(h1_hi); h2 = relu(h1@W2r + agg2@W2n + b2)
  agg_kernel<<<nodeBlocks, 256, 0, stream>>>(bE, csr, ofs, bC, bD, N);
  mgemm_kernel<2, true, true><<<gemmBlocks, 512, 0, stream>>>(
      bE, bF, bC, bD, whT + 2 * 16384, wlT + 2 * 16384, b2, bA, bB, N);  // h2 -> A,B

  // attention transform: ht = h2@Wa -> C,D
  mgemm_kernel<1, false, false><<<gemmBlocks, 512, 0, stream>>>(
      bA, bB, nullptr, nullptr, whT + 4 * 16384, wlT + 4 * 16384,
      nullptr, bC, bD, N);
  dots_kernel<<<nodeBlocks, 256, 0, stream>>>(bC, bD, a_src, a_dst, ssrc, sdst, N);
  attn_kernel<<<nodeBlocks, 256, 0, stream>>>(bC, csr, ofs, ssrc, sdst, outh, N);

  // output FC
  fc_kernel<<<nodeBlocks, 256, 0, stream>>>(outh, Wfc, bfc, (float*)d_out, N);
}

// Round 8
// 263.416 us; speedup vs baseline: 1.7097x; 1.0688x over previous
//
#include <hip/hip_runtime.h>
#include <cstddef>
#include <cstdint>

// ---------------------------------------------------------------------------
// GraphNeuralNetworkRiskManager: 2x GraphConv (sum-agg) + GAT attention + FC
// N=50000 nodes, E=800000 edges, F_IN=HID=128, F_OUT=2.
//
// Round 8 (on round-7 diagnosis: attn VALU fat + serial gather chain + fc
// re-read):
//   - attn: LDS-cached per-segment exp(e-m) (128 slots/wave, fallback
//     recompute), max-only first pass, PV loop has no random ssrc re-gather
//     and no exp; 1-deep software pipeline on the row gather; fc fused into
//     the epilogue (outh never materialized).
//   - agg: same 1-deep row-gather pipeline.
// CSR build: bucketed counting sort (round 7). GEMMs: bf16x3 MFMA staged
// via global_load_lds + XOR swizzle (round 6). Node tensors bf16 hi+lo.
// ---------------------------------------------------------------------------

typedef __attribute__((ext_vector_type(8))) short short8;
typedef __attribute__((ext_vector_type(4))) float f32x4;

#define NBUK 128
#define BSH  9          // bucket = dst >> 9 (512 nodes per bucket)
#define CHUNK 1568      // edges per bscatter block

__device__ __forceinline__ ushort f2b(float f) {       // fp32 -> bf16 bits, RNE
  uint32_t u = __float_as_uint(f);
  u += 0x7fffu + ((u >> 16) & 1u);
  return (ushort)(u >> 16);
}
__device__ __forceinline__ float b2f(ushort h) {       // bf16 bits -> fp32
  return __uint_as_float(((uint32_t)h) << 16);
}

__device__ __forceinline__ void gload_lds16(const void* g, void* l) {
  __builtin_amdgcn_global_load_lds(
      (const __attribute__((address_space(1))) void*)g,
      (__attribute__((address_space(3))) void*)l, 16, 0, 0);
}

// ---------------- fp32 -> (hi, lo) bf16 split of x ----------------

__global__ __launch_bounds__(256) void split_kernel(
    const float* __restrict__ in, ushort* __restrict__ hi,
    ushort* __restrict__ lo, int n) {
  int i = (blockIdx.x * blockDim.x + threadIdx.x) * 8;
  if (i >= n) return;
  float4 v0 = *(const float4*)(in + i);
  float4 v1 = *(const float4*)(in + i + 4);
  float v[8] = {v0.x, v0.y, v0.z, v0.w, v1.x, v1.y, v1.z, v1.w};
  short8 h, l;
  #pragma unroll
  for (int b = 0; b < 8; ++b) {
    ushort hh = f2b(v[b]);
    h[b] = (short)hh;
    l[b] = (short)f2b(v[b] - b2f(hh));
  }
  *(short8*)(hi + i) = h;
  *(short8*)(lo + i) = l;
}

// ---------------- W split+transpose: W[k][j] fp32 -> WhT/WlT[m][j][k] bf16 ----------------

__global__ __launch_bounds__(256) void wsplit_kernel(
    const float* __restrict__ W0, const float* __restrict__ W1,
    const float* __restrict__ W2, const float* __restrict__ W3,
    const float* __restrict__ W4,
    ushort* __restrict__ WhT, ushort* __restrict__ WlT) {
  __shared__ float tile[128][128];
  int m = blockIdx.x;
  const float* W = (m == 0) ? W0 : (m == 1) ? W1 : (m == 2) ? W2 : (m == 3) ? W3 : W4;
  int t = threadIdx.x;
  #pragma unroll
  for (int i = 0; i < 64; ++i) {
    int idx = i * 256 + t;                 // coalesced read
    tile[idx >> 7][idx & 127] = W[idx];
  }
  __syncthreads();
  int j = t >> 1, k0 = (t & 1) * 64;
  size_t obase = (size_t)m * 16384 + (size_t)j * 128 + k0;
  #pragma unroll
  for (int c = 0; c < 8; ++c) {
    short8 h, l;
    #pragma unroll
    for (int b = 0; b < 8; ++b) {
      float v = tile[k0 + c * 8 + b][j];
      ushort hh = f2b(v);
      h[b] = (short)hh;
      l[b] = (short)f2b(v - b2f(hh));
    }
    *(short8*)(WhT + obase + c * 8) = h;
    *(short8*)(WlT + obase + c * 8) = l;
  }
}

// ---------------- CSR build, bucketed ----------------

__global__ __launch_bounds__(256) void bhist_kernel(
    const int* __restrict__ ei, int E, int* __restrict__ bcnt) {
  __shared__ int lh[NBUK];
  int t = threadIdx.x;
  if (t < NBUK) lh[t] = 0;
  __syncthreads();
  int base = blockIdx.x * CHUNK;
  int lim = base + CHUNK; if (lim > E) lim = E;
  for (int i = base + t; i < lim; i += 256) atomicAdd(&lh[ei[E + i] >> BSH], 1);
  __syncthreads();
  if (t < NBUK && lh[t]) atomicAdd(&bcnt[t], lh[t]);
}

__global__ __launch_bounds__(256) void bscan_kernel(
    const int* __restrict__ bcnt, int* __restrict__ bbase,
    int* __restrict__ gtail) {
  __shared__ int sA[NBUK], sB[NBUK];
  int t = threadIdx.x;
  if (t < NBUK) sA[t] = bcnt[t];
  __syncthreads();
  int *s = sA, *d = sB;
  for (int st = 1; st < NBUK; st <<= 1) {
    if (t < NBUK) d[t] = s[t] + ((t >= st) ? s[t - st] : 0);
    __syncthreads();
    int* tmp = s; s = d; d = tmp;
  }
  if (t < NBUK) {
    int exc = (t == 0) ? 0 : s[t - 1];
    bbase[t] = exc;
    gtail[t] = exc;
  }
  if (t == 0) bbase[NBUK] = s[NBUK - 1];
}

__global__ __launch_bounds__(256) void bscatter_kernel(
    const int* __restrict__ ei, int E, int* __restrict__ gtail,
    uint2* __restrict__ pair) {
  __shared__ int lh[NBUK], sB[NBUK], lofs[NBUK], lcur[NBUK], gbase[NBUK];
  __shared__ uint2 buf[CHUNK];
  int t = threadIdx.x;
  if (t < NBUK) lh[t] = 0;
  __syncthreads();
  int base = blockIdx.x * CHUNK;
  int lim = base + CHUNK; if (lim > E) lim = E;
  for (int i = base + t; i < lim; i += 256) atomicAdd(&lh[ei[E + i] >> BSH], 1);
  __syncthreads();
  int *s = lh, *d = sB;
  for (int st = 1; st < NBUK; st <<= 1) {
    if (t < NBUK) d[t] = s[t] + ((t >= st) ? s[t - st] : 0);
    __syncthreads();
    int* tmp = s; s = d; d = tmp;
  }
  if (t < NBUK) {
    lofs[t] = (t == 0) ? 0 : s[t - 1];
    lcur[t] = lofs[t];
  }
  __syncthreads();
  for (int i = base + t; i < lim; i += 256) {
    int srcv = ei[i], dstv = ei[E + i];
    int p = atomicAdd(&lcur[dstv >> BSH], 1);
    buf[p] = make_uint2((unsigned)srcv, (unsigned)dstv);
  }
  __syncthreads();
  if (t < NBUK) {
    int c = s[t] - lofs[t];
    gbase[t] = c ? atomicAdd(&gtail[t], c) : 0;
  }
  __syncthreads();
  int n = lim - base;
  for (int i = t; i < n; i += 256) {
    uint2 pr = buf[i];
    int b = ((int)pr.y) >> BSH;
    pair[gbase[b] + (i - lofs[b])] = pr;
  }
}

__global__ __launch_bounds__(256) void csrbuild_kernel(
    const uint2* __restrict__ pair, const int* __restrict__ bbase,
    int* __restrict__ ofs, int* __restrict__ csr, int N, int E) {
  __shared__ int hA[512], hB[512];
  int b = blockIdx.x, t = threadIdx.x;
  int base = bbase[b], cnt = bbase[b + 1] - base;
  int node0 = b << BSH;
  int nn = N - node0; if (nn > 512) nn = 512;
  hA[t] = 0; hA[t + 256] = 0;
  __syncthreads();
  for (int i = t; i < cnt; i += 256)
    atomicAdd(&hA[(int)pair[base + i].y - node0], 1);
  __syncthreads();
  int *s = hA, *d = hB;
  for (int st = 1; st < 512; st <<= 1) {
    #pragma unroll
    for (int k = 0; k < 2; ++k) {
      int i = t + k * 256;
      d[i] = s[i] + ((i >= st) ? s[i - st] : 0);
    }
    __syncthreads();
    int* tmp = s; s = d; d = tmp;
  }
  #pragma unroll
  for (int k = 0; k < 2; ++k) {
    int i = t + k * 256;
    if (i < nn) ofs[node0 + i] = base + (i == 0 ? 0 : s[i - 1]);
  }
  if (t == 0 && node0 + nn >= N) ofs[N] = E;
  #pragma unroll
  for (int k = 0; k < 2; ++k) {
    int i = t + k * 256;
    d[i] = (i == 0 ? 0 : s[i - 1]);
  }
  __syncthreads();
  for (int i = t; i < cnt; i += 256) {
    uint2 pr = pair[base + i];
    int p = atomicAdd(&d[(int)pr.y - node0], 1);
    csr[base + p] = (int)pr.x;
  }
}

// ---------------- CSR sum-aggregation, 4-edge groups, pipelined gather ----------------

__global__ __launch_bounds__(256) void agg_kernel(
    const ushort* __restrict__ Xh, const int* __restrict__ csr,
    const int* __restrict__ ofs, ushort* __restrict__ Gh,
    ushort* __restrict__ Gl, int N) {
  int node = (blockIdx.x * blockDim.x + threadIdx.x) >> 6;
  int lane = threadIdx.x & 63;
  if (node >= N) return;
  int g = lane >> 4, q = lane & 15;
  int beg = ofs[node], end = ofs[node + 1];
  float a[8] = {};
  int p = beg + g;
  if (p < end) {
    int s = csr[p];
    short8 v = *(const short8*)(Xh + (size_t)s * 128 + q * 8);
    for (p += 4; p < end; p += 4) {
      int s2 = csr[p];                       // next index (L1-resident)
      short8 v2 = *(const short8*)(Xh + (size_t)s2 * 128 + q * 8);  // in flight
      #pragma unroll
      for (int b = 0; b < 8; ++b) a[b] += b2f((ushort)v[b]);
      v = v2;
    }
    #pragma unroll
    for (int b = 0; b < 8; ++b) a[b] += b2f((ushort)v[b]);
  }
  #pragma unroll
  for (int b = 0; b < 8; ++b) {
    a[b] += __shfl_xor(a[b], 16);
    a[b] += __shfl_xor(a[b], 32);
  }
  if (lane < 16) {
    short8 h, l;
    #pragma unroll
    for (int b = 0; b < 8; ++b) {
      ushort hh = f2b(a[b]);
      h[b] = (short)hh;
      l[b] = (short)f2b(a[b] - b2f(hh));
    }
    *(short8*)(Gh + (size_t)node * 128 + q * 8) = h;
    *(short8*)(Gl + (size_t)node * 128 + q * 8) = l;
  }
}

// ---------------- bf16x3 MFMA GEMM, LDS-staged (m97 pattern) ----------------

template <int S, bool RELU, bool BIAS>
__global__ __launch_bounds__(512, 2) void mgemm_kernel(
    const ushort* __restrict__ A1h, const ushort* __restrict__ A1l,
    const ushort* __restrict__ A2h, const ushort* __restrict__ A2l,
    const ushort* __restrict__ WhT, const ushort* __restrict__ WlT,
    const float* __restrict__ bias,
    ushort* __restrict__ Ch, ushort* __restrict__ Cl, int M) {
  __shared__ char lds[2 * S * 16384];   // 2S tiles of 16 KB (64 rows x 256 B)
  int t = threadIdx.x;
  int l = t & 63;
  int w = t >> 6;
  int j = (w << 4) + (l & 15);      // output column
  int krow0 = (l >> 4) * 8;         // k offset within 32-wide k-step
  int rowBase = blockIdx.x * 64;

  const ushort* srcs[4] = {A1h, A1l, (S > 1) ? A2h : A1h, (S > 1) ? A2l : A1l};
  int ldsWaveBase0 = (t & ~63) * 16;             // uniform per wave, part 0
  #pragma unroll
  for (int q = 0; q < 2 * S; ++q) {
    const char* gsrc = (const char*)srcs[q];
    #pragma unroll
    for (int part = 0; part < 2; ++part) {
      int c = part * 512 + t;                    // chunk id 0..1023
      int r = c >> 4;                            // tile row
      int cb = (c & 15) << 4;                    // byte col within row
      int row = rowBase + r;
      if (row >= M) row = M - 1;
      int sb = cb ^ ((r & 7) << 4);              // inverse-swizzled source col
      gload_lds16(gsrc + (size_t)row * 256 + sb,
                  &lds[q * 16384 + part * 8192 + ldsWaveBase0]);
    }
  }

  short8 wh[S][4], wl[S][4];
  #pragma unroll
  for (int s = 0; s < S; ++s) {
    #pragma unroll
    for (int ks = 0; ks < 4; ++ks) {
      size_t wb = (size_t)s * 16384 + (size_t)j * 128 + ks * 32 + krow0;
      wh[s][ks] = *(const short8*)(WhT + wb);
      wl[s][ks] = *(const short8*)(WlT + wb);
    }
  }

  __syncthreads();   // drains vmcnt (global_load_lds)

  f32x4 acc[4];
  #pragma unroll
  for (int i = 0; i < 4; ++i) acc[i] = (f32x4){0.f, 0.f, 0.f, 0.f};

  #pragma unroll
  for (int rf = 0; rf < 4; ++rf) {
    int r = rf * 16 + (l & 15);
    int sw = (r & 7) << 4;
    int rb = r * 256;
    #pragma unroll
    for (int s = 0; s < S; ++s) {
      #pragma unroll
      for (int ks = 0; ks < 4; ++ks) {
        int off = rb + ((ks * 64 + (l >> 4) * 16) ^ sw);
        short8 ah = *(const short8*)&lds[(s * 2 + 0) * 16384 + off];
        short8 al = *(const short8*)&lds[(s * 2 + 1) * 16384 + off];
        acc[rf] = __builtin_amdgcn_mfma_f32_16x16x32_bf16(al, wh[s][ks], acc[rf], 0, 0, 0);
        acc[rf] = __builtin_amdgcn_mfma_f32_16x16x32_bf16(ah, wl[s][ks], acc[rf], 0, 0, 0);
        acc[rf] = __builtin_amdgcn_mfma_f32_16x16x32_bf16(ah, wh[s][ks], acc[rf], 0, 0, 0);
      }
    }
  }

  float bj = BIAS ? bias[j] : 0.f;
  #pragma unroll
  for (int rf = 0; rf < 4; ++rf) {
    int rbase = rowBase + rf * 16 + (l >> 4) * 4;
    #pragma unroll
    for (int r = 0; r < 4; ++r) {
      int row = rbase + r;
      if (row < M) {
        float v = acc[rf][r];
        if (BIAS) v += bj;
        if (RELU) v = fmaxf(v, 0.f);
        ushort h = f2b(v);
        Ch[(size_t)row * 128 + j] = h;
        Cl[(size_t)row * 128 + j] = f2b(v - b2f(h));
      }
    }
  }
}

// ---------------- per-node dots: s_src = ht.a_src, s_dst = ht.a_dst ----------------

__global__ __launch_bounds__(256) void dots_kernel(
    const ushort* __restrict__ HTh, const ushort* __restrict__ HTl,
    const float* __restrict__ a_src, const float* __restrict__ a_dst,
    float* __restrict__ ssrc, float* __restrict__ sdst, int N) {
  int n = (blockIdx.x * blockDim.x + threadIdx.x) >> 6;
  int lane = threadIdx.x & 63;
  if (n >= N) return;
  uint uh = ((const uint*)(HTh + (size_t)n * 128))[lane];
  uint ul = ((const uint*)(HTl + (size_t)n * 128))[lane];
  float h0 = b2f((ushort)(uh & 0xffff)) + b2f((ushort)(ul & 0xffff));
  float h1 = b2f((ushort)(uh >> 16)) + b2f((ushort)(ul >> 16));
  float vs = h0 * a_src[2 * lane] + h1 * a_src[2 * lane + 1];
  float vd = h0 * a_dst[2 * lane] + h1 * a_dst[2 * lane + 1];
  #pragma unroll
  for (int d = 32; d > 0; d >>= 1) {
    vs += __shfl_xor(vs, d);
    vd += __shfl_xor(vd, d);
  }
  if (lane == 0) { ssrc[n] = vs; sdst[n] = vd; }
}

// ---------------- fused attention + FC ----------------
// Per node (one wave): pass 1 gathers scores, caches e in LDS (<=128 slots),
// max-reduce; pass 2 sums exp(e-m) from LDS (stores unnormalized weight back);
// pass 3 weighted PV with pipelined row gather; epilogue applies Wfc in-reg.

__global__ __launch_bounds__(256) void attn_kernel(
    const ushort* __restrict__ HTh, const int* __restrict__ csr,
    const int* __restrict__ ofs, const float* __restrict__ ssrc,
    const float* __restrict__ sdst, const float* __restrict__ Wfc,
    const float* __restrict__ bfc, float* __restrict__ out, int N) {
  __shared__ float eld[4][128];
  int wv = (threadIdx.x >> 6) & 3;
  int n = (blockIdx.x * blockDim.x + threadIdx.x) >> 6;
  int lane = threadIdx.x & 63;
  if (n >= N) return;
  int beg = ofs[n], end = ofs[n + 1];
  int deg = end - beg;
  float sd = sdst[n];

  // pass 1: gather scores, cache in LDS, max only
  float m = -3.4e38f;
  for (int i = lane; i < deg; i += 64) {
    float e = ssrc[csr[beg + i]] + sd;
    e = (e >= 0.f) ? e : 0.2f * e;
    if (i < 128) eld[wv][i] = e;
    m = fmaxf(m, e);
  }
  #pragma unroll
  for (int d = 32; d > 0; d >>= 1) m = fmaxf(m, __shfl_xor(m, d));

  // pass 2: denom from LDS; store unnormalized weight back
  float ssum = 0.f;
  for (int i = lane; i < deg; i += 64) {
    float e;
    if (i < 128) e = eld[wv][i];
    else {
      e = ssrc[csr[beg + i]] + sd;
      e = (e >= 0.f) ? e : 0.2f * e;
    }
    float t = __expf(e - m);
    if (i < 128) eld[wv][i] = t;
    ssum += t;
  }
  #pragma unroll
  for (int d = 32; d > 0; d >>= 1) ssum += __shfl_xor(ssum, d);
  float inv = 1.0f / (ssum + 1e-16f);

  // pass 3: weighted PV, 4-edge groups, 1-deep pipelined row gather
  int g = lane >> 4, q = lane & 15;
  float a[8] = {};
  int i = g;
  if (i < deg) {
    int s = csr[beg + i];
    short8 v = *(const short8*)(HTh + (size_t)s * 128 + q * 8);
    float t;
    if (i < 128) t = eld[wv][i];
    else {
      float e = ssrc[s] + sd;
      e = (e >= 0.f) ? e : 0.2f * e;
      t = __expf(e - m);
    }
    for (i += 4; i < deg; i += 4) {
      int s2 = csr[beg + i];
      short8 v2 = *(const short8*)(HTh + (size_t)s2 * 128 + q * 8);  // in flight
      float t2;
      if (i < 128) t2 = eld[wv][i];
      else {
        float e2 = ssrc[s2] + sd;
        e2 = (e2 >= 0.f) ? e2 : 0.2f * e2;
        t2 = __expf(e2 - m);
      }
      float wgt = t * inv;
      #pragma unroll
      for (int b = 0; b < 8; ++b) a[b] += wgt * b2f((ushort)v[b]);
      v = v2; t = t2;
    }
    float wgt = t * inv;
    #pragma unroll
    for (int b = 0; b < 8; ++b) a[b] += wgt * b2f((ushort)v[b]);
  }
  #pragma unroll
  for (int b = 0; b < 8; ++b) {
    a[b] += __shfl_xor(a[b], 16);
    a[b] += __shfl_xor(a[b], 32);
  }

  // fused FC: lane q holds outh[n][q*8 .. q*8+7]; Wfc rows are [128][2]
  float4 wf0 = *(const float4*)(Wfc + q * 16);
  float4 wf1 = *(const float4*)(Wfc + q * 16 + 4);
  float4 wf2 = *(const float4*)(Wfc + q * 16 + 8);
  float4 wf3 = *(const float4*)(Wfc + q * 16 + 12);
  float o0 = a[0] * wf0.x + a[1] * wf0.z + a[2] * wf1.x + a[3] * wf1.z +
             a[4] * wf2.x + a[5] * wf2.z + a[6] * wf3.x + a[7] * wf3.z;
  float o1 = a[0] * wf0.y + a[1] * wf0.w + a[2] * wf1.y + a[3] * wf1.w +
             a[4] * wf2.y + a[5] * wf2.w + a[6] * wf3.y + a[7] * wf3.w;
  #pragma unroll
  for (int d = 1; d < 16; d <<= 1) {
    o0 += __shfl_xor(o0, d);
    o1 += __shfl_xor(o1, d);
  }
  if (lane == 0) {
    out[(size_t)n * 2 + 0] = o0 + bfc[0];
    out[(size_t)n * 2 + 1] = o1 + bfc[1];
  }
}

// ---------------- launch ----------------

static inline size_t align_up(size_t x, size_t a) { return (x + a - 1) & ~(a - 1); }

extern "C" void kernel_launch(void* const* d_in, const int* in_sizes, int n_in,
                              void* d_out, int out_size, void* d_ws, size_t ws_size,
                              hipStream_t stream) {
  const float* x     = (const float*)d_in[0];
  const int*   ei    = (const int*)d_in[1];
  const float* W1r   = (const float*)d_in[2];
  const float* W1n   = (const float*)d_in[3];
  const float* b1    = (const float*)d_in[4];
  const float* W2r   = (const float*)d_in[5];
  const float* W2n   = (const float*)d_in[6];
  const float* b2    = (const float*)d_in[7];
  const float* Wa    = (const float*)d_in[8];
  const float* a_src = (const float*)d_in[9];
  const float* a_dst = (const float*)d_in[10];
  const float* Wfc   = (const float*)d_in[11];
  const float* bfc   = (const float*)d_in[12];

  const int N = in_sizes[0] / 128;   // 50000
  const int E = in_sizes[1] / 2;     // 800000

  // workspace carve-up
  char* ws = (char*)d_ws;
  size_t off = 0;
  auto take = [&](size_t bytes) {
    char* p = ws + off;
    off = align_up(off + bytes, 256);
    return p;
  };
  const size_t NB = (size_t)N * 128 * 2;  // one bf16 node tensor (12.8 MB)
  int*    ofs   = (int*)take((size_t)(N + 1) * 4);
  int*    csr   = (int*)take((size_t)E * 4);
  int*    bcnt  = (int*)take(NBUK * 4);
  int*    bbase = (int*)take((NBUK + 1) * 4);
  int*    gtail = (int*)take(NBUK * 4);
  uint2*  pair  = (uint2*)take((size_t)E * 8);
  float*  ssrc  = (float*)take((size_t)N * 4);
  float*  sdst  = (float*)take((size_t)N * 4);
  ushort* whT   = (ushort*)take((size_t)5 * 16384 * 2);  // pre-split W hi
  ushort* wlT   = (ushort*)take((size_t)5 * 16384 * 2);  // pre-split W lo
  ushort* bA    = (ushort*)take(NB);   // x_hi  -> h2_hi
  ushort* bB    = (ushort*)take(NB);   // x_lo  -> h2_lo
  ushort* bC    = (ushort*)take(NB);   // g_hi  -> ht_hi
  ushort* bD    = (ushort*)take(NB);   // g_lo  -> ht_lo
  ushort* bE    = (ushort*)take(NB);   // h1_hi
  ushort* bF    = (ushort*)take(NB);   // h1_lo

  hipMemsetAsync(bcnt, 0, NBUK * 4, stream);

  const int nodeBlocks = (N + 3) / 4;     // 4 waves per 256-thread block
  const int gemmBlocks = (N + 63) / 64;   // 64-row LDS-staged tiles
  const int splitBlocks = (N * 128 / 8 + 255) / 256;
  const int chunkBlocks = (E + CHUNK - 1) / CHUNK;
  const int bukBlocks   = (N + 511) / 512;

  // W pre-split (mats: 0=W1r 1=W1n 2=W2r 3=W2n 4=Wa), x split, CSR build
  wsplit_kernel<<<5, 256, 0, stream>>>(W1r, W1n, W2r, W2n, Wa, whT, wlT);
  split_kernel<<<splitBlocks, 256, 0, stream>>>(x, bA, bB, N * 128);
  bhist_kernel<<<chunkBlocks, 256, 0, stream>>>(ei, E, bcnt);
  bscan_kernel<<<1, 256, 0, stream>>>(bcnt, bbase, gtail);
  bscatter_kernel<<<chunkBlocks, 256, 0, stream>>>(ei, E, gtail, pair);
  csrbuild_kernel<<<bukBlocks, 256, 0, stream>>>(pair, bbase, ofs, csr, N, E);

  // layer 1: agg1 = sum(x_hi); h1 = relu(x@W1r + agg1@W1n + b1)
  agg_kernel<<<nodeBlocks, 256, 0, stream>>>(bA, csr, ofs, bC, bD, N);
  mgemm_kernel<2, true, true><<<gemmBlocks, 512, 0, stream>>>(
      bA, bB, bC, bD, whT, wlT, b1, bE, bF, N);                    // h1 -> E,F

  // layer 2: agg2 = sum(h1_hi); h2 = relu(h1@W2r + agg2@W2n + b2)
  agg_kernel<<<nodeBlocks, 256, 0, stream>>>(bE, csr, ofs, bC, bD, N);
  mgemm_kernel<2, true, true><<<gemmBlocks, 512, 0, stream>>>(
      bE, bF, bC, bD, whT + 2 * 16384, wlT + 2 * 16384, b2, bA, bB, N);  // h2 -> A,B

  // attention transform: ht = h2@Wa -> C,D
  mgemm_kernel<1, false, false><<<gemmBlocks, 512, 0, stream>>>(
      bA, bB, nullptr, nullptr, whT + 4 * 16384, wlT + 4 * 16384,
      nullptr, bC, bD, N);
  dots_kernel<<<nodeBlocks, 256, 0, stream>>>(bC, bD, a_src, a_dst, ssrc, sdst, N);

  // fused attention softmax + PV + FC -> out
  attn_kernel<<<nodeBlocks, 256, 0, stream>>>(
      bC, csr, ofs, ssrc, sdst, Wfc, bfc, (float*)d_out, N);
}

// Round 9
// 260.384 us; speedup vs baseline: 1.7296x; 1.0116x over previous
//
#include <hip/hip_runtime.h>
#include <cstddef>
#include <cstdint>

// ---------------------------------------------------------------------------
// GraphNeuralNetworkRiskManager: 2x GraphConv (sum-agg) + GAT attention + FC
// N=50000 nodes, E=800000 edges, F_IN=HID=128, F_OUT=2.
//
// Round 9 (on round-8 diagnosis: attn/agg bound by random row gather +
// inner-loop VALU; dots re-reads 25.6 MB the Wa-GEMM already has in regs):
//   - 2-deep pipelined row gather in attn PV and agg; inv applied once.
//   - rows loaded as uint4, bf16->f32 via shift/mask (2 VALU per feature).
//   - dots fused into Wa-mgemm epilogue (shfl col-reduce + LDS cross-wave).
// CSR build: bucketed counting sort. GEMMs: bf16x3 MFMA via global_load_lds
// + XOR swizzle. Node tensors bf16 hi+lo pairs. FC fused into attn.
// ---------------------------------------------------------------------------

typedef __attribute__((ext_vector_type(8))) short short8;
typedef __attribute__((ext_vector_type(4))) float f32x4;

#define NBUK 128
#define BSH  9          // bucket = dst >> 9 (512 nodes per bucket)
#define CHUNK 1568      // edges per bscatter block

__device__ __forceinline__ ushort f2b(float f) {       // fp32 -> bf16 bits, RNE
  uint32_t u = __float_as_uint(f);
  u += 0x7fffu + ((u >> 16) & 1u);
  return (ushort)(u >> 16);
}
__device__ __forceinline__ float b2f(ushort h) {       // bf16 bits -> fp32
  return __uint_as_float(((uint32_t)h) << 16);
}
__device__ __forceinline__ float blo(uint32_t u) { return __uint_as_float(u << 16); }
__device__ __forceinline__ float bhi(uint32_t u) { return __uint_as_float(u & 0xffff0000u); }

__device__ __forceinline__ void gload_lds16(const void* g, void* l) {
  __builtin_amdgcn_global_load_lds(
      (const __attribute__((address_space(1))) void*)g,
      (__attribute__((address_space(3))) void*)l, 16, 0, 0);
}

// unweighted accumulate of 8 bf16 features packed in uint4
#define ACC8(A, V)                                     \
  { A[0] += blo(V.x); A[1] += bhi(V.x);                \
    A[2] += blo(V.y); A[3] += bhi(V.y);                \
    A[4] += blo(V.z); A[5] += bhi(V.z);                \
    A[6] += blo(V.w); A[7] += bhi(V.w); }

// weighted accumulate
#define ACC8W(A, V, T)                                 \
  { A[0] += (T) * blo(V.x); A[1] += (T) * bhi(V.x);    \
    A[2] += (T) * blo(V.y); A[3] += (T) * bhi(V.y);    \
    A[4] += (T) * blo(V.z); A[5] += (T) * bhi(V.z);    \
    A[6] += (T) * blo(V.w); A[7] += (T) * bhi(V.w); }

// ---------------- fp32 -> (hi, lo) bf16 split of x ----------------

__global__ __launch_bounds__(256) void split_kernel(
    const float* __restrict__ in, ushort* __restrict__ hi,
    ushort* __restrict__ lo, int n) {
  int i = (blockIdx.x * blockDim.x + threadIdx.x) * 8;
  if (i >= n) return;
  float4 v0 = *(const float4*)(in + i);
  float4 v1 = *(const float4*)(in + i + 4);
  float v[8] = {v0.x, v0.y, v0.z, v0.w, v1.x, v1.y, v1.z, v1.w};
  short8 h, l;
  #pragma unroll
  for (int b = 0; b < 8; ++b) {
    ushort hh = f2b(v[b]);
    h[b] = (short)hh;
    l[b] = (short)f2b(v[b] - b2f(hh));
  }
  *(short8*)(hi + i) = h;
  *(short8*)(lo + i) = l;
}

// ---------------- W split+transpose: W[k][j] fp32 -> WhT/WlT[m][j][k] bf16 ----------------

__global__ __launch_bounds__(256) void wsplit_kernel(
    const float* __restrict__ W0, const float* __restrict__ W1,
    const float* __restrict__ W2, const float* __restrict__ W3,
    const float* __restrict__ W4,
    ushort* __restrict__ WhT, ushort* __restrict__ WlT) {
  __shared__ float tile[128][128];
  int m = blockIdx.x;
  const float* W = (m == 0) ? W0 : (m == 1) ? W1 : (m == 2) ? W2 : (m == 3) ? W3 : W4;
  int t = threadIdx.x;
  #pragma unroll
  for (int i = 0; i < 64; ++i) {
    int idx = i * 256 + t;                 // coalesced read
    tile[idx >> 7][idx & 127] = W[idx];
  }
  __syncthreads();
  int j = t >> 1, k0 = (t & 1) * 64;
  size_t obase = (size_t)m * 16384 + (size_t)j * 128 + k0;
  #pragma unroll
  for (int c = 0; c < 8; ++c) {
    short8 h, l;
    #pragma unroll
    for (int b = 0; b < 8; ++b) {
      float v = tile[k0 + c * 8 + b][j];
      ushort hh = f2b(v);
      h[b] = (short)hh;
      l[b] = (short)f2b(v - b2f(hh));
    }
    *(short8*)(WhT + obase + c * 8) = h;
    *(short8*)(WlT + obase + c * 8) = l;
  }
}

// ---------------- CSR build, bucketed ----------------

__global__ __launch_bounds__(256) void bhist_kernel(
    const int* __restrict__ ei, int E, int* __restrict__ bcnt) {
  __shared__ int lh[NBUK];
  int t = threadIdx.x;
  if (t < NBUK) lh[t] = 0;
  __syncthreads();
  int base = blockIdx.x * CHUNK;
  int lim = base + CHUNK; if (lim > E) lim = E;
  for (int i = base + t; i < lim; i += 256) atomicAdd(&lh[ei[E + i] >> BSH], 1);
  __syncthreads();
  if (t < NBUK && lh[t]) atomicAdd(&bcnt[t], lh[t]);
}

__global__ __launch_bounds__(256) void bscan_kernel(
    const int* __restrict__ bcnt, int* __restrict__ bbase,
    int* __restrict__ gtail) {
  __shared__ int sA[NBUK], sB[NBUK];
  int t = threadIdx.x;
  if (t < NBUK) sA[t] = bcnt[t];
  __syncthreads();
  int *s = sA, *d = sB;
  for (int st = 1; st < NBUK; st <<= 1) {
    if (t < NBUK) d[t] = s[t] + ((t >= st) ? s[t - st] : 0);
    __syncthreads();
    int* tmp = s; s = d; d = tmp;
  }
  if (t < NBUK) {
    int exc = (t == 0) ? 0 : s[t - 1];
    bbase[t] = exc;
    gtail[t] = exc;
  }
  if (t == 0) bbase[NBUK] = s[NBUK - 1];
}

__global__ __launch_bounds__(256) void bscatter_kernel(
    const int* __restrict__ ei, int E, int* __restrict__ gtail,
    uint2* __restrict__ pair) {
  __shared__ int lh[NBUK], sB[NBUK], lofs[NBUK], lcur[NBUK], gbase[NBUK];
  __shared__ uint2 buf[CHUNK];
  int t = threadIdx.x;
  if (t < NBUK) lh[t] = 0;
  __syncthreads();
  int base = blockIdx.x * CHUNK;
  int lim = base + CHUNK; if (lim > E) lim = E;
  for (int i = base + t; i < lim; i += 256) atomicAdd(&lh[ei[E + i] >> BSH], 1);
  __syncthreads();
  int *s = lh, *d = sB;
  for (int st = 1; st < NBUK; st <<= 1) {
    if (t < NBUK) d[t] = s[t] + ((t >= st) ? s[t - st] : 0);
    __syncthreads();
    int* tmp = s; s = d; d = tmp;
  }
  if (t < NBUK) {
    lofs[t] = (t == 0) ? 0 : s[t - 1];
    lcur[t] = lofs[t];
  }
  __syncthreads();
  for (int i = base + t; i < lim; i += 256) {
    int srcv = ei[i], dstv = ei[E + i];
    int p = atomicAdd(&lcur[dstv >> BSH], 1);
    buf[p] = make_uint2((unsigned)srcv, (unsigned)dstv);
  }
  __syncthreads();
  if (t < NBUK) {
    int c = s[t] - lofs[t];
    gbase[t] = c ? atomicAdd(&gtail[t], c) : 0;
  }
  __syncthreads();
  int n = lim - base;
  for (int i = t; i < n; i += 256) {
    uint2 pr = buf[i];
    int b = ((int)pr.y) >> BSH;
    pair[gbase[b] + (i - lofs[b])] = pr;
  }
}

__global__ __launch_bounds__(256) void csrbuild_kernel(
    const uint2* __restrict__ pair, const int* __restrict__ bbase,
    int* __restrict__ ofs, int* __restrict__ csr, int N, int E) {
  __shared__ int hA[512], hB[512];
  int b = blockIdx.x, t = threadIdx.x;
  int base = bbase[b], cnt = bbase[b + 1] - base;
  int node0 = b << BSH;
  int nn = N - node0; if (nn > 512) nn = 512;
  hA[t] = 0; hA[t + 256] = 0;
  __syncthreads();
  for (int i = t; i < cnt; i += 256)
    atomicAdd(&hA[(int)pair[base + i].y - node0], 1);
  __syncthreads();
  int *s = hA, *d = hB;
  for (int st = 1; st < 512; st <<= 1) {
    #pragma unroll
    for (int k = 0; k < 2; ++k) {
      int i = t + k * 256;
      d[i] = s[i] + ((i >= st) ? s[i - st] : 0);
    }
    __syncthreads();
    int* tmp = s; s = d; d = tmp;
  }
  #pragma unroll
  for (int k = 0; k < 2; ++k) {
    int i = t + k * 256;
    if (i < nn) ofs[node0 + i] = base + (i == 0 ? 0 : s[i - 1]);
  }
  if (t == 0 && node0 + nn >= N) ofs[N] = E;
  #pragma unroll
  for (int k = 0; k < 2; ++k) {
    int i = t + k * 256;
    d[i] = (i == 0 ? 0 : s[i - 1]);
  }
  __syncthreads();
  for (int i = t; i < cnt; i += 256) {
    uint2 pr = pair[base + i];
    int p = atomicAdd(&d[(int)pr.y - node0], 1);
    csr[base + p] = (int)pr.x;
  }
}

// ---------------- CSR sum-aggregation, 4-edge groups, 2-deep pipeline ----------------

__global__ __launch_bounds__(256) void agg_kernel(
    const ushort* __restrict__ Xh, const int* __restrict__ csr,
    const int* __restrict__ ofs, ushort* __restrict__ Gh,
    ushort* __restrict__ Gl, int N) {
  int node = (blockIdx.x * blockDim.x + threadIdx.x) >> 6;
  int lane = threadIdx.x & 63;
  if (node >= N) return;
  int g = lane >> 4, q = lane & 15;
  int beg = ofs[node], end = ofs[node + 1];
  float a[8] = {};
  int p = beg + g;
  if (p < end) {
    uint4 v0 = *(const uint4*)(Xh + (size_t)csr[p] * 128 + q * 8);
    int p1 = p + 4;
    if (p1 < end) {
      uint4 v1 = *(const uint4*)(Xh + (size_t)csr[p1] * 128 + q * 8);
      for (int pn = p1 + 4; pn < end; pn += 4) {
        uint4 v2 = *(const uint4*)(Xh + (size_t)csr[pn] * 128 + q * 8);  // in flight
        ACC8(a, v0);
        v0 = v1; v1 = v2;
      }
      ACC8(a, v0);
      v0 = v1;
    }
    ACC8(a, v0);
  }
  #pragma unroll
  for (int b = 0; b < 8; ++b) {
    a[b] += __shfl_xor(a[b], 16);
    a[b] += __shfl_xor(a[b], 32);
  }
  if (lane < 16) {
    short8 h, l;
    #pragma unroll
    for (int b = 0; b < 8; ++b) {
      ushort hh = f2b(a[b]);
      h[b] = (short)hh;
      l[b] = (short)f2b(a[b] - b2f(hh));
    }
    *(short8*)(Gh + (size_t)node * 128 + q * 8) = h;
    *(short8*)(Gl + (size_t)node * 128 + q * 8) = l;
  }
}

// ---------------- bf16x3 MFMA GEMM, LDS-staged; optional fused dots ----------------

template <int S, bool RELU, bool BIAS, bool DOTS>
__global__ __launch_bounds__(512, 2) void mgemm_kernel(
    const ushort* __restrict__ A1h, const ushort* __restrict__ A1l,
    const ushort* __restrict__ A2h, const ushort* __restrict__ A2l,
    const ushort* __restrict__ WhT, const ushort* __restrict__ WlT,
    const float* __restrict__ bias,
    const float* __restrict__ asp, const float* __restrict__ adp,
    float* __restrict__ ssrc, float* __restrict__ sdst,
    ushort* __restrict__ Ch, ushort* __restrict__ Cl, int M) {
  __shared__ char lds[2 * S * 16384];   // 2S tiles of 16 KB (64 rows x 256 B)
  __shared__ float pm[DOTS ? 8 * 128 : 1];
  int t = threadIdx.x;
  int l = t & 63;
  int w = t >> 6;
  int j = (w << 4) + (l & 15);      // output column
  int krow0 = (l >> 4) * 8;         // k offset within 32-wide k-step
  int rowBase = blockIdx.x * 64;

  const ushort* srcs[4] = {A1h, A1l, (S > 1) ? A2h : A1h, (S > 1) ? A2l : A1l};
  int ldsWaveBase0 = (t & ~63) * 16;             // uniform per wave, part 0
  #pragma unroll
  for (int q = 0; q < 2 * S; ++q) {
    const char* gsrc = (const char*)srcs[q];
    #pragma unroll
    for (int part = 0; part < 2; ++part) {
      int c = part * 512 + t;                    // chunk id 0..1023
      int r = c >> 4;                            // tile row
      int cb = (c & 15) << 4;                    // byte col within row
      int row = rowBase + r;
      if (row >= M) row = M - 1;
      int sb = cb ^ ((r & 7) << 4);              // inverse-swizzled source col
      gload_lds16(gsrc + (size_t)row * 256 + sb,
                  &lds[q * 16384 + part * 8192 + ldsWaveBase0]);
    }
  }

  short8 wh[S][4], wl[S][4];
  #pragma unroll
  for (int s = 0; s < S; ++s) {
    #pragma unroll
    for (int ks = 0; ks < 4; ++ks) {
      size_t wb = (size_t)s * 16384 + (size_t)j * 128 + ks * 32 + krow0;
      wh[s][ks] = *(const short8*)(WhT + wb);
      wl[s][ks] = *(const short8*)(WlT + wb);
    }
  }

  __syncthreads();   // drains vmcnt (global_load_lds)

  f32x4 acc[4];
  #pragma unroll
  for (int i = 0; i < 4; ++i) acc[i] = (f32x4){0.f, 0.f, 0.f, 0.f};

  #pragma unroll
  for (int rf = 0; rf < 4; ++rf) {
    int r = rf * 16 + (l & 15);
    int sw = (r & 7) << 4;
    int rb = r * 256;
    #pragma unroll
    for (int s = 0; s < S; ++s) {
      #pragma unroll
      for (int ks = 0; ks < 4; ++ks) {
        int off = rb + ((ks * 64 + (l >> 4) * 16) ^ sw);
        short8 ah = *(const short8*)&lds[(s * 2 + 0) * 16384 + off];
        short8 al = *(const short8*)&lds[(s * 2 + 1) * 16384 + off];
        acc[rf] = __builtin_amdgcn_mfma_f32_16x16x32_bf16(al, wh[s][ks], acc[rf], 0, 0, 0);
        acc[rf] = __builtin_amdgcn_mfma_f32_16x16x32_bf16(ah, wl[s][ks], acc[rf], 0, 0, 0);
        acc[rf] = __builtin_amdgcn_mfma_f32_16x16x32_bf16(ah, wh[s][ks], acc[rf], 0, 0, 0);
      }
    }
  }

  float bj = BIAS ? bias[j] : 0.f;
  #pragma unroll
  for (int rf = 0; rf < 4; ++rf) {
    int rbase = rowBase + rf * 16 + (l >> 4) * 4;
    #pragma unroll
    for (int r = 0; r < 4; ++r) {
      int row = rbase + r;
      if (row < M) {
        float v = acc[rf][r];
        if (BIAS) v += bj;
        if (RELU) v = fmaxf(v, 0.f);
        ushort h = f2b(v);
        Ch[(size_t)row * 128 + j] = h;
        Cl[(size_t)row * 128 + j] = f2b(v - b2f(h));
      }
    }
  }

  if constexpr (DOTS) {
    // s_src/s_dst: per-thread partial over its column, shfl-reduce the 16
    // cols of this wave, then cross-wave combine in LDS.
    float as_ = asp[j], ad_ = adp[j];
    #pragma unroll
    for (int rf = 0; rf < 4; ++rf) {
      #pragma unroll
      for (int r = 0; r < 4; ++r) {
        float v = acc[rf][r];
        float vs = v * as_, vd = v * ad_;
        #pragma unroll
        for (int d = 1; d < 16; d <<= 1) {
          vs += __shfl_xor(vs, d);
          vd += __shfl_xor(vd, d);
        }
        if ((l & 15) == 0) {
          int rl = rf * 16 + (l >> 4) * 4 + r;
          pm[w * 128 + rl * 2 + 0] = vs;
          pm[w * 128 + rl * 2 + 1] = vd;
        }
      }
    }
    __syncthreads();
    if (t < 64) {
      int row = rowBase + t;
      if (row < M) {
        float vs = 0.f, vd = 0.f;
        #pragma unroll
        for (int ww = 0; ww < 8; ++ww) {
          vs += pm[ww * 128 + t * 2 + 0];
          vd += pm[ww * 128 + t * 2 + 1];
        }
        ssrc[row] = vs;
        sdst[row] = vd;
      }
    }
  }
}

// ---------------- fused attention + FC ----------------
// Per node (one wave): pass 1 gathers scores, caches e in LDS (<=128 slots),
// max-reduce; pass 2 exps from LDS (stores unnormalized weight back); pass 3
// weighted PV with 2-deep pipelined row gather; epilogue applies Wfc in-reg.

__global__ __launch_bounds__(256) void attn_kernel(
    const ushort* __restrict__ HTh, const int* __restrict__ csr,
    const int* __restrict__ ofs, const float* __restrict__ ssrc,
    const float* __restrict__ sdst, const float* __restrict__ Wfc,
    const float* __restrict__ bfc, float* __restrict__ out, int N) {
  __shared__ float eld[4][128];
  int wv = (threadIdx.x >> 6) & 3;
  int n = (blockIdx.x * blockDim.x + threadIdx.x) >> 6;
  int lane = threadIdx.x & 63;
  if (n >= N) return;
  int beg = ofs[n], end = ofs[n + 1];
  int deg = end - beg;
  float sd = sdst[n];

  // pass 1: gather scores, cache in LDS, max only
  float m = -3.4e38f;
  for (int i = lane; i < deg; i += 64) {
    float e = ssrc[csr[beg + i]] + sd;
    e = (e >= 0.f) ? e : 0.2f * e;
    if (i < 128) eld[wv][i] = e;
    m = fmaxf(m, e);
  }
  #pragma unroll
  for (int d = 32; d > 0; d >>= 1) m = fmaxf(m, __shfl_xor(m, d));

  // pass 2: denom from LDS; store unnormalized weight back
  float ssum = 0.f;
  for (int i = lane; i < deg; i += 64) {
    float e;
    if (i < 128) e = eld[wv][i];
    else {
      e = ssrc[csr[beg + i]] + sd;
      e = (e >= 0.f) ? e : 0.2f * e;
    }
    float t = __expf(e - m);
    if (i < 128) eld[wv][i] = t;
    ssum += t;
  }
  #pragma unroll
  for (int d = 32; d > 0; d >>= 1) ssum += __shfl_xor(ssum, d);
  float inv = 1.0f / (ssum + 1e-16f);

  // pass 3: unnormalized weighted PV, 4-edge groups, 2-deep pipeline
  int g = lane >> 4, q = lane & 15;
  float a[8] = {};
  int i0 = g;
  if (i0 < deg) {
    int s0 = csr[beg + i0];
    uint4 v0 = *(const uint4*)(HTh + (size_t)s0 * 128 + q * 8);
    float t0;
    if (i0 < 128) t0 = eld[wv][i0];
    else {
      float e = ssrc[s0] + sd;
      e = (e >= 0.f) ? e : 0.2f * e;
      t0 = __expf(e - m);
    }
    int i1 = i0 + 4;
    if (i1 < deg) {
      int s1 = csr[beg + i1];
      uint4 v1 = *(const uint4*)(HTh + (size_t)s1 * 128 + q * 8);
      float t1;
      if (i1 < 128) t1 = eld[wv][i1];
      else {
        float e = ssrc[s1] + sd;
        e = (e >= 0.f) ? e : 0.2f * e;
        t1 = __expf(e - m);
      }
      for (int i2 = i1 + 4; i2 < deg; i2 += 4) {
        int s2 = csr[beg + i2];
        uint4 v2 = *(const uint4*)(HTh + (size_t)s2 * 128 + q * 8);  // in flight
        float t2;
        if (i2 < 128) t2 = eld[wv][i2];
        else {
          float e = ssrc[s2] + sd;
          e = (e >= 0.f) ? e : 0.2f * e;
          t2 = __expf(e - m);
        }
        ACC8W(a, v0, t0);
        v0 = v1; t0 = t1; v1 = v2; t1 = t2;
      }
      ACC8W(a, v0, t0);
      v0 = v1; t0 = t1;
    }
    ACC8W(a, v0, t0);
  }
  #pragma unroll
  for (int b = 0; b < 8; ++b) {
    a[b] += __shfl_xor(a[b], 16);
    a[b] += __shfl_xor(a[b], 32);
    a[b] *= inv;                    // normalize once
  }

  // fused FC: lane q holds outh[n][q*8 .. q*8+7]; Wfc rows are [128][2]
  float4 wf0 = *(const float4*)(Wfc + q * 16);
  float4 wf1 = *(const float4*)(Wfc + q * 16 + 4);
  float4 wf2 = *(const float4*)(Wfc + q * 16 + 8);
  float4 wf3 = *(const float4*)(Wfc + q * 16 + 12);
  float o0 = a[0] * wf0.x + a[1] * wf0.z + a[2] * wf1.x + a[3] * wf1.z +
             a[4] * wf2.x + a[5] * wf2.z + a[6] * wf3.x + a[7] * wf3.z;
  float o1 = a[0] * wf0.y + a[1] * wf0.w + a[2] * wf1.y + a[3] * wf1.w +
             a[4] * wf2.y + a[5] * wf2.w + a[6] * wf3.y + a[7] * wf3.w;
  #pragma unroll
  for (int d = 1; d < 16; d <<= 1) {
    o0 += __shfl_xor(o0, d);
    o1 += __shfl_xor(o1, d);
  }
  if (lane == 0) {
    out[(size_t)n * 2 + 0] = o0 + bfc[0];
    out[(size_t)n * 2 + 1] = o1 + bfc[1];
  }
}

// ---------------- launch ----------------

static inline size_t align_up(size_t x, size_t a) { return (x + a - 1) & ~(a - 1); }

extern "C" void kernel_launch(void* const* d_in, const int* in_sizes, int n_in,
                              void* d_out, int out_size, void* d_ws, size_t ws_size,
                              hipStream_t stream) {
  const float* x     = (const float*)d_in[0];
  const int*   ei    = (const int*)d_in[1];
  const float* W1r   = (const float*)d_in[2];
  const float* W1n   = (const float*)d_in[3];
  const float* b1    = (const float*)d_in[4];
  const float* W2r   = (const float*)d_in[5];
  const float* W2n   = (const float*)d_in[6];
  const float* b2    = (const float*)d_in[7];
  const float* Wa    = (const float*)d_in[8];
  const float* a_src = (const float*)d_in[9];
  const float* a_dst = (const float*)d_in[10];
  const float* Wfc   = (const float*)d_in[11];
  const float* bfc   = (const float*)d_in[12];

  const int N = in_sizes[0] / 128;   // 50000
  const int E = in_sizes[1] / 2;     // 800000

  // workspace carve-up
  char* ws = (char*)d_ws;
  size_t off = 0;
  auto take = [&](size_t bytes) {
    char* p = ws + off;
    off = align_up(off + bytes, 256);
    return p;
  };
  const size_t NB = (size_t)N * 128 * 2;  // one bf16 node tensor (12.8 MB)
  int*    ofs   = (int*)take((size_t)(N + 1) * 4);
  int*    csr   = (int*)take((size_t)E * 4);
  int*    bcnt  = (int*)take(NBUK * 4);
  int*    bbase = (int*)take((NBUK + 1) * 4);
  int*    gtail = (int*)take(NBUK * 4);
  uint2*  pair  = (uint2*)take((size_t)E * 8);
  float*  ssrc  = (float*)take((size_t)N * 4);
  float*  sdst  = (float*)take((size_t)N * 4);
  ushort* whT   = (ushort*)take((size_t)5 * 16384 * 2);  // pre-split W hi
  ushort* wlT   = (ushort*)take((size_t)5 * 16384 * 2);  // pre-split W lo
  ushort* bA    = (ushort*)take(NB);   // x_hi  -> h2_hi
  ushort* bB    = (ushort*)take(NB);   // x_lo  -> h2_lo
  ushort* bC    = (ushort*)take(NB);   // g_hi  -> ht_hi
  ushort* bD    = (ushort*)take(NB);   // g_lo  -> ht_lo
  ushort* bE    = (ushort*)take(NB);   // h1_hi
  ushort* bF    = (ushort*)take(NB);   // h1_lo

  hipMemsetAsync(bcnt, 0, NBUK * 4, stream);

  const int nodeBlocks = (N + 3) / 4;     // 4 waves per 256-thread block
  const int gemmBlocks = (N + 63) / 64;   // 64-row LDS-staged tiles
  const int splitBlocks = (N * 128 / 8 + 255) / 256;
  const int chunkBlocks = (E + CHUNK - 1) / CHUNK;
  const int bukBlocks   = (N + 511) / 512;

  // W pre-split (mats: 0=W1r 1=W1n 2=W2r 3=W2n 4=Wa), x split, CSR build
  wsplit_kernel<<<5, 256, 0, stream>>>(W1r, W1n, W2r, W2n, Wa, whT, wlT);
  split_kernel<<<splitBlocks, 256, 0, stream>>>(x, bA, bB, N * 128);
  bhist_kernel<<<chunkBlocks, 256, 0, stream>>>(ei, E, bcnt);
  bscan_kernel<<<1, 256, 0, stream>>>(bcnt, bbase, gtail);
  bscatter_kernel<<<chunkBlocks, 256, 0, stream>>>(ei, E, gtail, pair);
  csrbuild_kernel<<<bukBlocks, 256, 0, stream>>>(pair, bbase, ofs, csr, N, E);

  // layer 1: agg1 = sum(x_hi); h1 = relu(x@W1r + agg1@W1n + b1)
  agg_kernel<<<nodeBlocks, 256, 0, stream>>>(bA, csr, ofs, bC, bD, N);
  mgemm_kernel<2, true, true, false><<<gemmBlocks, 512, 0, stream>>>(
      bA, bB, bC, bD, whT, wlT, b1, nullptr, nullptr, nullptr, nullptr,
      bE, bF, N);                                                   // h1 -> E,F

  // layer 2: agg2 = sum(h1_hi); h2 = relu(h1@W2r + agg2@W2n + b2)
  agg_kernel<<<nodeBlocks, 256, 0, stream>>>(bE, csr, ofs, bC, bD, N);
  mgemm_kernel<2, true, true, false><<<gemmBlocks, 512, 0, stream>>>(
      bE, bF, bC, bD, whT + 2 * 16384, wlT + 2 * 16384, b2, nullptr, nullptr,
      nullptr, nullptr, bA, bB, N);                                 // h2 -> A,B

  // attention transform: ht = h2@Wa -> C,D  (+ fused s_src/s_dst dots)
  mgemm_kernel<1, false, false, true><<<gemmBlocks, 512, 0, stream>>>(
      bA, bB, nullptr, nullptr, whT + 4 * 16384, wlT + 4 * 16384, nullptr,
      a_src, a_dst, ssrc, sdst, bC, bD, N);

  // fused attention softmax + PV + FC -> out
  attn_kernel<<<nodeBlocks, 256, 0, stream>>>(
      bC, csr, ofs, ssrc, sdst, Wfc, bfc, (float*)d_out, N);
}

// Round 11
// 256.559 us; speedup vs baseline: 1.7554x; 1.0149x over previous
//
#include <hip/hip_runtime.h>
#include <cstddef>
#include <cstdint>

// ---------------------------------------------------------------------------
// GraphNeuralNetworkRiskManager: 2x GraphConv (sum-agg) + GAT attention + FC
// N=50000 nodes, E=800000 edges, F_IN=HID=128, F_OUT=2.
//
// Round 11 = round 10 with the divergent-shfl bug fixed:
//   attn fast path's PV loop now has a WAVE-UNIFORM trip count
//   (trips = ceil(deg/16)); every __shfl executes with all 64 lanes active.
//   Round-10 bug: shfl inside a group-divergent loop read t/s_ from lanes
//   whose groups had exited -- ds_bpermute from exec-off lanes is undefined.
// attn: deg<=64 register softmax (lane-per-edge), blocks-of-16 masked PV
// gathers, fused FC. agg: blocks-of-16 masked gathers. CSR: bucketed
// counting sort. GEMMs: bf16x3 MFMA via global_load_lds + XOR swizzle;
// dots fused in Wa-GEMM epilogue. Node tensors bf16 hi+lo pairs.
// ---------------------------------------------------------------------------

typedef __attribute__((ext_vector_type(8))) short short8;
typedef __attribute__((ext_vector_type(4))) float f32x4;

#define NBUK 128
#define BSH  9          // bucket = dst >> 9 (512 nodes per bucket)
#define CHUNK 1568      // edges per bscatter block

__device__ __forceinline__ ushort f2b(float f) {       // fp32 -> bf16 bits, RNE
  uint32_t u = __float_as_uint(f);
  u += 0x7fffu + ((u >> 16) & 1u);
  return (ushort)(u >> 16);
}
__device__ __forceinline__ float b2f(ushort h) {       // bf16 bits -> fp32
  return __uint_as_float(((uint32_t)h) << 16);
}
__device__ __forceinline__ float blo(uint32_t u) { return __uint_as_float(u << 16); }
__device__ __forceinline__ float bhi(uint32_t u) { return __uint_as_float(u & 0xffff0000u); }

__device__ __forceinline__ void gload_lds16(const void* g, void* l) {
  __builtin_amdgcn_global_load_lds(
      (const __attribute__((address_space(1))) void*)g,
      (__attribute__((address_space(3))) void*)l, 16, 0, 0);
}

#define ACC8(A, V)                                     \
  { A[0] += blo(V.x); A[1] += bhi(V.x);                \
    A[2] += blo(V.y); A[3] += bhi(V.y);                \
    A[4] += blo(V.z); A[5] += bhi(V.z);                \
    A[6] += blo(V.w); A[7] += bhi(V.w); }

#define ACC8W(A, V, T)                                 \
  { A[0] += (T) * blo(V.x); A[1] += (T) * bhi(V.x);    \
    A[2] += (T) * blo(V.y); A[3] += (T) * bhi(V.y);    \
    A[4] += (T) * blo(V.z); A[5] += (T) * bhi(V.z);    \
    A[6] += (T) * blo(V.w); A[7] += (T) * bhi(V.w); }

// ---------------- fp32 -> (hi, lo) bf16 split of x ----------------

__global__ __launch_bounds__(256) void split_kernel(
    const float* __restrict__ in, ushort* __restrict__ hi,
    ushort* __restrict__ lo, int n) {
  int i = (blockIdx.x * blockDim.x + threadIdx.x) * 8;
  if (i >= n) return;
  float4 v0 = *(const float4*)(in + i);
  float4 v1 = *(const float4*)(in + i + 4);
  float v[8] = {v0.x, v0.y, v0.z, v0.w, v1.x, v1.y, v1.z, v1.w};
  short8 h, l;
  #pragma unroll
  for (int b = 0; b < 8; ++b) {
    ushort hh = f2b(v[b]);
    h[b] = (short)hh;
    l[b] = (short)f2b(v[b] - b2f(hh));
  }
  *(short8*)(hi + i) = h;
  *(short8*)(lo + i) = l;
}

// ---------------- W split+transpose: W[k][j] fp32 -> WhT/WlT[m][j][k] bf16 ----------------

__global__ __launch_bounds__(256) void wsplit_kernel(
    const float* __restrict__ W0, const float* __restrict__ W1,
    const float* __restrict__ W2, const float* __restrict__ W3,
    const float* __restrict__ W4,
    ushort* __restrict__ WhT, ushort* __restrict__ WlT) {
  __shared__ float tile[128][128];
  int m = blockIdx.x;
  const float* W = (m == 0) ? W0 : (m == 1) ? W1 : (m == 2) ? W2 : (m == 3) ? W3 : W4;
  int t = threadIdx.x;
  #pragma unroll
  for (int i = 0; i < 64; ++i) {
    int idx = i * 256 + t;                 // coalesced read
    tile[idx >> 7][idx & 127] = W[idx];
  }
  __syncthreads();
  int j = t >> 1, k0 = (t & 1) * 64;
  size_t obase = (size_t)m * 16384 + (size_t)j * 128 + k0;
  #pragma unroll
  for (int c = 0; c < 8; ++c) {
    short8 h, l;
    #pragma unroll
    for (int b = 0; b < 8; ++b) {
      float v = tile[k0 + c * 8 + b][j];
      ushort hh = f2b(v);
      h[b] = (short)hh;
      l[b] = (short)f2b(v - b2f(hh));
    }
    *(short8*)(WhT + obase + c * 8) = h;
    *(short8*)(WlT + obase + c * 8) = l;
  }
}

// ---------------- CSR build, bucketed ----------------

__global__ __launch_bounds__(256) void bhist_kernel(
    const int* __restrict__ ei, int E, int* __restrict__ bcnt) {
  __shared__ int lh[NBUK];
  int t = threadIdx.x;
  if (t < NBUK) lh[t] = 0;
  __syncthreads();
  int base = blockIdx.x * CHUNK;
  int lim = base + CHUNK; if (lim > E) lim = E;
  for (int i = base + t; i < lim; i += 256) atomicAdd(&lh[ei[E + i] >> BSH], 1);
  __syncthreads();
  if (t < NBUK && lh[t]) atomicAdd(&bcnt[t], lh[t]);
}

__global__ __launch_bounds__(256) void bscan_kernel(
    const int* __restrict__ bcnt, int* __restrict__ bbase,
    int* __restrict__ gtail) {
  __shared__ int sA[NBUK], sB[NBUK];
  int t = threadIdx.x;
  if (t < NBUK) sA[t] = bcnt[t];
  __syncthreads();
  int *s = sA, *d = sB;
  for (int st = 1; st < NBUK; st <<= 1) {
    if (t < NBUK) d[t] = s[t] + ((t >= st) ? s[t - st] : 0);
    __syncthreads();
    int* tmp = s; s = d; d = tmp;
  }
  if (t < NBUK) {
    int exc = (t == 0) ? 0 : s[t - 1];
    bbase[t] = exc;
    gtail[t] = exc;
  }
  if (t == 0) bbase[NBUK] = s[NBUK - 1];
}

__global__ __launch_bounds__(256) void bscatter_kernel(
    const int* __restrict__ ei, int E, int* __restrict__ gtail,
    uint2* __restrict__ pair) {
  __shared__ int lh[NBUK], sB[NBUK], lofs[NBUK], lcur[NBUK], gbase[NBUK];
  __shared__ uint2 buf[CHUNK];
  int t = threadIdx.x;
  if (t < NBUK) lh[t] = 0;
  __syncthreads();
  int base = blockIdx.x * CHUNK;
  int lim = base + CHUNK; if (lim > E) lim = E;
  for (int i = base + t; i < lim; i += 256) atomicAdd(&lh[ei[E + i] >> BSH], 1);
  __syncthreads();
  int *s = lh, *d = sB;
  for (int st = 1; st < NBUK; st <<= 1) {
    if (t < NBUK) d[t] = s[t] + ((t >= st) ? s[t - st] : 0);
    __syncthreads();
    int* tmp = s; s = d; d = tmp;
  }
  if (t < NBUK) {
    lofs[t] = (t == 0) ? 0 : s[t - 1];
    lcur[t] = lofs[t];
  }
  __syncthreads();
  for (int i = base + t; i < lim; i += 256) {
    int srcv = ei[i], dstv = ei[E + i];
    int p = atomicAdd(&lcur[dstv >> BSH], 1);
    buf[p] = make_uint2((unsigned)srcv, (unsigned)dstv);
  }
  __syncthreads();
  if (t < NBUK) {
    int c = s[t] - lofs[t];
    gbase[t] = c ? atomicAdd(&gtail[t], c) : 0;
  }
  __syncthreads();
  int n = lim - base;
  for (int i = t; i < n; i += 256) {
    uint2 pr = buf[i];
    int b = ((int)pr.y) >> BSH;
    pair[gbase[b] + (i - lofs[b])] = pr;
  }
}

__global__ __launch_bounds__(256) void csrbuild_kernel(
    const uint2* __restrict__ pair, const int* __restrict__ bbase,
    int* __restrict__ ofs, int* __restrict__ csr, int N, int E) {
  __shared__ int hA[512], hB[512];
  int b = blockIdx.x, t = threadIdx.x;
  int base = bbase[b], cnt = bbase[b + 1] - base;
  int node0 = b << BSH;
  int nn = N - node0; if (nn > 512) nn = 512;
  hA[t] = 0; hA[t + 256] = 0;
  __syncthreads();
  for (int i = t; i < cnt; i += 256)
    atomicAdd(&hA[(int)pair[base + i].y - node0], 1);
  __syncthreads();
  int *s = hA, *d = hB;
  for (int st = 1; st < 512; st <<= 1) {
    #pragma unroll
    for (int k = 0; k < 2; ++k) {
      int i = t + k * 256;
      d[i] = s[i] + ((i >= st) ? s[i - st] : 0);
    }
    __syncthreads();
    int* tmp = s; s = d; d = tmp;
  }
  #pragma unroll
  for (int k = 0; k < 2; ++k) {
    int i = t + k * 256;
    if (i < nn) ofs[node0 + i] = base + (i == 0 ? 0 : s[i - 1]);
  }
  if (t == 0 && node0 + nn >= N) ofs[N] = E;
  #pragma unroll
  for (int k = 0; k < 2; ++k) {
    int i = t + k * 256;
    d[i] = (i == 0 ? 0 : s[i - 1]);
  }
  __syncthreads();
  for (int i = t; i < cnt; i += 256) {
    uint2 pr = pair[base + i];
    int p = atomicAdd(&d[(int)pr.y - node0], 1);
    csr[base + p] = (int)pr.x;
  }
}

// ---------------- CSR sum-aggregation: blocks-of-16 masked gathers ----------------

__global__ __launch_bounds__(256) void agg_kernel(
    const ushort* __restrict__ Xh, const int* __restrict__ csr,
    const int* __restrict__ ofs, ushort* __restrict__ Gh,
    ushort* __restrict__ Gl, int N) {
  int node = (blockIdx.x * blockDim.x + threadIdx.x) >> 6;
  int lane = threadIdx.x & 63;
  if (node >= N) return;
  int g = lane >> 4, q = lane & 15;
  int beg = ofs[node], end = ofs[node + 1];
  int deg = end - beg;
  float a[8] = {};
  for (int base = g; base < deg; base += 16) {
    int ib = base + 4, ic = base + 8, id = base + 12;
    int sa = csr[beg + base];
    int sb = csr[beg + ((ib < deg) ? ib : 0)];
    int sc = csr[beg + ((ic < deg) ? ic : 0)];
    int se = csr[beg + ((id < deg) ? id : 0)];
    uint4 va = *(const uint4*)(Xh + (size_t)sa * 128 + q * 8);
    uint4 vb = *(const uint4*)(Xh + (size_t)sb * 128 + q * 8);
    uint4 vc = *(const uint4*)(Xh + (size_t)sc * 128 + q * 8);
    uint4 vd = *(const uint4*)(Xh + (size_t)se * 128 + q * 8);
    ACC8(a, va);
    if (ib < deg) ACC8(a, vb);
    if (ic < deg) ACC8(a, vc);
    if (id < deg) ACC8(a, vd);
  }
  #pragma unroll
  for (int b = 0; b < 8; ++b) {
    a[b] += __shfl_xor(a[b], 16);
    a[b] += __shfl_xor(a[b], 32);
  }
  if (lane < 16) {
    short8 h, l;
    #pragma unroll
    for (int b = 0; b < 8; ++b) {
      ushort hh = f2b(a[b]);
      h[b] = (short)hh;
      l[b] = (short)f2b(a[b] - b2f(hh));
    }
    *(short8*)(Gh + (size_t)node * 128 + q * 8) = h;
    *(short8*)(Gl + (size_t)node * 128 + q * 8) = l;
  }
}

// ---------------- bf16x3 MFMA GEMM, LDS-staged; optional fused dots ----------------

template <int S, bool RELU, bool BIAS, bool DOTS>
__global__ __launch_bounds__(512, 2) void mgemm_kernel(
    const ushort* __restrict__ A1h, const ushort* __restrict__ A1l,
    const ushort* __restrict__ A2h, const ushort* __restrict__ A2l,
    const ushort* __restrict__ WhT, const ushort* __restrict__ WlT,
    const float* __restrict__ bias,
    const float* __restrict__ asp, const float* __restrict__ adp,
    float* __restrict__ ssrc, float* __restrict__ sdst,
    ushort* __restrict__ Ch, ushort* __restrict__ Cl, int M) {
  __shared__ char lds[2 * S * 16384];   // 2S tiles of 16 KB (64 rows x 256 B)
  __shared__ float pm[DOTS ? 8 * 128 : 1];
  int t = threadIdx.x;
  int l = t & 63;
  int w = t >> 6;
  int j = (w << 4) + (l & 15);      // output column
  int krow0 = (l >> 4) * 8;         // k offset within 32-wide k-step
  int rowBase = blockIdx.x * 64;

  const ushort* srcs[4] = {A1h, A1l, (S > 1) ? A2h : A1h, (S > 1) ? A2l : A1l};
  int ldsWaveBase0 = (t & ~63) * 16;             // uniform per wave, part 0
  #pragma unroll
  for (int q = 0; q < 2 * S; ++q) {
    const char* gsrc = (const char*)srcs[q];
    #pragma unroll
    for (int part = 0; part < 2; ++part) {
      int c = part * 512 + t;                    // chunk id 0..1023
      int r = c >> 4;                            // tile row
      int cb = (c & 15) << 4;                    // byte col within row
      int row = rowBase + r;
      if (row >= M) row = M - 1;
      int sb = cb ^ ((r & 7) << 4);              // inverse-swizzled source col
      gload_lds16(gsrc + (size_t)row * 256 + sb,
                  &lds[q * 16384 + part * 8192 + ldsWaveBase0]);
    }
  }

  short8 wh[S][4], wl[S][4];
  #pragma unroll
  for (int s = 0; s < S; ++s) {
    #pragma unroll
    for (int ks = 0; ks < 4; ++ks) {
      size_t wb = (size_t)s * 16384 + (size_t)j * 128 + ks * 32 + krow0;
      wh[s][ks] = *(const short8*)(WhT + wb);
      wl[s][ks] = *(const short8*)(WlT + wb);
    }
  }

  __syncthreads();   // drains vmcnt (global_load_lds)

  f32x4 acc[4];
  #pragma unroll
  for (int i = 0; i < 4; ++i) acc[i] = (f32x4){0.f, 0.f, 0.f, 0.f};

  #pragma unroll
  for (int rf = 0; rf < 4; ++rf) {
    int r = rf * 16 + (l & 15);
    int sw = (r & 7) << 4;
    int rb = r * 256;
    #pragma unroll
    for (int s = 0; s < S; ++s) {
      #pragma unroll
      for (int ks = 0; ks < 4; ++ks) {
        int off = rb + ((ks * 64 + (l >> 4) * 16) ^ sw);
        short8 ah = *(const short8*)&lds[(s * 2 + 0) * 16384 + off];
        short8 al = *(const short8*)&lds[(s * 2 + 1) * 16384 + off];
        acc[rf] = __builtin_amdgcn_mfma_f32_16x16x32_bf16(al, wh[s][ks], acc[rf], 0, 0, 0);
        acc[rf] = __builtin_amdgcn_mfma_f32_16x16x32_bf16(ah, wl[s][ks], acc[rf], 0, 0, 0);
        acc[rf] = __builtin_amdgcn_mfma_f32_16x16x32_bf16(ah, wh[s][ks], acc[rf], 0, 0, 0);
      }
    }
  }

  float bj = BIAS ? bias[j] : 0.f;
  #pragma unroll
  for (int rf = 0; rf < 4; ++rf) {
    int rbase = rowBase + rf * 16 + (l >> 4) * 4;
    #pragma unroll
    for (int r = 0; r < 4; ++r) {
      int row = rbase + r;
      if (row < M) {
        float v = acc[rf][r];
        if (BIAS) v += bj;
        if (RELU) v = fmaxf(v, 0.f);
        ushort h = f2b(v);
        Ch[(size_t)row * 128 + j] = h;
        Cl[(size_t)row * 128 + j] = f2b(v - b2f(h));
      }
    }
  }

  if constexpr (DOTS) {
    float as_ = asp[j], ad_ = adp[j];
    #pragma unroll
    for (int rf = 0; rf < 4; ++rf) {
      #pragma unroll
      for (int r = 0; r < 4; ++r) {
        float v = acc[rf][r];
        float vs = v * as_, vd = v * ad_;
        #pragma unroll
        for (int d = 1; d < 16; d <<= 1) {
          vs += __shfl_xor(vs, d);
          vd += __shfl_xor(vd, d);
        }
        if ((l & 15) == 0) {
          int rl = rf * 16 + (l >> 4) * 4 + r;
          pm[w * 128 + rl * 2 + 0] = vs;
          pm[w * 128 + rl * 2 + 1] = vd;
        }
      }
    }
    __syncthreads();
    if (t < 64) {
      int row = rowBase + t;
      if (row < M) {
        float vs = 0.f, vd = 0.f;
        #pragma unroll
        for (int ww = 0; ww < 8; ++ww) {
          vs += pm[ww * 128 + t * 2 + 0];
          vd += pm[ww * 128 + t * 2 + 1];
        }
        ssrc[row] = vs;
        sdst[row] = vd;
      }
    }
  }
}

// ---------------- fused attention + FC ----------------
// deg<=64 fast path: lane i owns edge i -- register softmax, then PV with a
// WAVE-UNIFORM trip count (all lanes run all iterations; shfl sources always
// active; per-slot weights masked to 0). deg>64 fallback: 3-pass recompute.

__global__ __launch_bounds__(256) void attn_kernel(
    const ushort* __restrict__ HTh, const int* __restrict__ csr,
    const int* __restrict__ ofs, const float* __restrict__ ssrc,
    const float* __restrict__ sdst, const float* __restrict__ Wfc,
    const float* __restrict__ bfc, float* __restrict__ out, int N) {
  int n = (blockIdx.x * blockDim.x + threadIdx.x) >> 6;
  int lane = threadIdx.x & 63;
  if (n >= N) return;
  int beg = ofs[n], end = ofs[n + 1];
  int deg = end - beg;
  float sd = sdst[n];
  int g = lane >> 4, q = lane & 15;
  float a[8] = {};
  float inv = 0.f;

  if (deg > 0 && deg <= 64) {
    // register softmax: lane i holds edge beg+i
    int s_ = csr[beg + ((lane < deg) ? lane : 0)];
    float e = ssrc[s_] + sd;
    e = (e >= 0.f) ? e : 0.2f * e;
    float m = (lane < deg) ? e : -3.4e38f;
    #pragma unroll
    for (int d = 32; d > 0; d >>= 1) m = fmaxf(m, __shfl_xor(m, d));
    float t = (lane < deg) ? __expf(e - m) : 0.f;
    float ssum = t;
    #pragma unroll
    for (int d = 32; d > 0; d >>= 1) ssum += __shfl_xor(ssum, d);
    inv = 1.0f / (ssum + 1e-16f);

    // PV: uniform trip count -> no divergence around __shfl (round-10 fix)
    int trips = (deg + 15) >> 4;
    for (int k = 0; k < trips; ++k) {
      int ia = k * 16 + g;
      int ib = ia + 4, ic = ia + 8, id = ia + 12;
      int sa = __shfl(s_, ia & 63);
      int sb = __shfl(s_, ib & 63);
      int sc = __shfl(s_, ic & 63);
      int se = __shfl(s_, id & 63);
      float ta0 = __shfl(t, ia & 63);
      float tb0 = __shfl(t, ib & 63);
      float tc0 = __shfl(t, ic & 63);
      float td0 = __shfl(t, id & 63);
      float ta = (ia < deg) ? ta0 : 0.f;
      float tb = (ib < deg) ? tb0 : 0.f;
      float tc = (ic < deg) ? tc0 : 0.f;
      float td = (id < deg) ? td0 : 0.f;
      uint4 va = *(const uint4*)(HTh + (size_t)sa * 128 + q * 8);
      uint4 vb = *(const uint4*)(HTh + (size_t)sb * 128 + q * 8);
      uint4 vc = *(const uint4*)(HTh + (size_t)sc * 128 + q * 8);
      uint4 vd = *(const uint4*)(HTh + (size_t)se * 128 + q * 8);
      ACC8W(a, va, ta);
      ACC8W(a, vb, tb);
      ACC8W(a, vc, tc);
      ACC8W(a, vd, td);
    }
  } else if (deg > 64) {
    // fallback: 3-pass with recompute
    float m = -3.4e38f;
    for (int i = lane; i < deg; i += 64) {
      float e = ssrc[csr[beg + i]] + sd;
      e = (e >= 0.f) ? e : 0.2f * e;
      m = fmaxf(m, e);
    }
    #pragma unroll
    for (int d = 32; d > 0; d >>= 1) m = fmaxf(m, __shfl_xor(m, d));
    float ssum = 0.f;
    for (int i = lane; i < deg; i += 64) {
      float e = ssrc[csr[beg + i]] + sd;
      e = (e >= 0.f) ? e : 0.2f * e;
      ssum += __expf(e - m);
    }
    #pragma unroll
    for (int d = 32; d > 0; d >>= 1) ssum += __shfl_xor(ssum, d);
    inv = 1.0f / (ssum + 1e-16f);
    for (int i = g; i < deg; i += 4) {
      int s = csr[beg + i];
      float e = ssrc[s] + sd;
      e = (e >= 0.f) ? e : 0.2f * e;
      float t = __expf(e - m);
      uint4 v = *(const uint4*)(HTh + (size_t)s * 128 + q * 8);
      ACC8W(a, v, t);
    }
  }

  #pragma unroll
  for (int b = 0; b < 8; ++b) {
    a[b] += __shfl_xor(a[b], 16);
    a[b] += __shfl_xor(a[b], 32);
    a[b] *= inv;                    // normalize once (deg==0: a stays 0)
  }

  // fused FC: lane q holds outh[n][q*8 .. q*8+7]; Wfc rows are [128][2]
  float4 wf0 = *(const float4*)(Wfc + q * 16);
  float4 wf1 = *(const float4*)(Wfc + q * 16 + 4);
  float4 wf2 = *(const float4*)(Wfc + q * 16 + 8);
  float4 wf3 = *(const float4*)(Wfc + q * 16 + 12);
  float o0 = a[0] * wf0.x + a[1] * wf0.z + a[2] * wf1.x + a[3] * wf1.z +
             a[4] * wf2.x + a[5] * wf2.z + a[6] * wf3.x + a[7] * wf3.z;
  float o1 = a[0] * wf0.y + a[1] * wf0.w + a[2] * wf1.y + a[3] * wf1.w +
             a[4] * wf2.y + a[5] * wf2.w + a[6] * wf3.y + a[7] * wf3.w;
  #pragma unroll
  for (int d = 1; d < 16; d <<= 1) {
    o0 += __shfl_xor(o0, d);
    o1 += __shfl_xor(o1, d);
  }
  if (lane == 0) {
    out[(size_t)n * 2 + 0] = o0 + bfc[0];
    out[(size_t)n * 2 + 1] = o1 + bfc[1];
  }
}

// ---------------- launch ----------------

static inline size_t align_up(size_t x, size_t a) { return (x + a - 1) & ~(a - 1); }

extern "C" void kernel_launch(void* const* d_in, const int* in_sizes, int n_in,
                              void* d_out, int out_size, void* d_ws, size_t ws_size,
                              hipStream_t stream) {
  const float* x     = (const float*)d_in[0];
  const int*   ei    = (const int*)d_in[1];
  const float* W1r   = (const float*)d_in[2];
  const float* W1n   = (const float*)d_in[3];
  const float* b1    = (const float*)d_in[4];
  const float* W2r   = (const float*)d_in[5];
  const float* W2n   = (const float*)d_in[6];
  const float* b2    = (const float*)d_in[7];
  const float* Wa    = (const float*)d_in[8];
  const float* a_src = (const float*)d_in[9];
  const float* a_dst = (const float*)d_in[10];
  const float* Wfc   = (const float*)d_in[11];
  const float* bfc   = (const float*)d_in[12];

  const int N = in_sizes[0] / 128;   // 50000
  const int E = in_sizes[1] / 2;     // 800000

  // workspace carve-up
  char* ws = (char*)d_ws;
  size_t off = 0;
  auto take = [&](size_t bytes) {
    char* p = ws + off;
    off = align_up(off + bytes, 256);
    return p;
  };
  const size_t NB = (size_t)N * 128 * 2;  // one bf16 node tensor (12.8 MB)
  int*    ofs   = (int*)take((size_t)(N + 1) * 4);
  int*    csr   = (int*)take((size_t)E * 4);
  int*    bcnt  = (int*)take(NBUK * 4);
  int*    bbase = (int*)take((NBUK + 1) * 4);
  int*    gtail = (int*)take(NBUK * 4);
  uint2*  pair  = (uint2*)take((size_t)E * 8);
  float*  ssrc  = (float*)take((size_t)N * 4);
  float*  sdst  = (float*)take((size_t)N * 4);
  ushort* whT   = (ushort*)take((size_t)5 * 16384 * 2);  // pre-split W hi
  ushort* wlT   = (ushort*)take((size_t)5 * 16384 * 2);  // pre-split W lo
  ushort* bA    = (ushort*)take(NB);   // x_hi  -> h2_hi
  ushort* bB    = (ushort*)take(NB);   // x_lo  -> h2_lo
  ushort* bC    = (ushort*)take(NB);   // g_hi  -> ht_hi
  ushort* bD    = (ushort*)take(NB);   // g_lo  -> ht_lo
  ushort* bE    = (ushort*)take(NB);   // h1_hi
  ushort* bF    = (ushort*)take(NB);   // h1_lo

  hipMemsetAsync(bcnt, 0, NBUK * 4, stream);

  const int nodeBlocks = (N + 3) / 4;     // 4 waves per 256-thread block
  const int gemmBlocks = (N + 63) / 64;   // 64-row LDS-staged tiles
  const int splitBlocks = (N * 128 / 8 + 255) / 256;
  const int chunkBlocks = (E + CHUNK - 1) / CHUNK;
  const int bukBlocks   = (N + 511) / 512;

  // W pre-split (mats: 0=W1r 1=W1n 2=W2r 3=W2n 4=Wa), x split, CSR build
  wsplit_kernel<<<5, 256, 0, stream>>>(W1r, W1n, W2r, W2n, Wa, whT, wlT);
  split_kernel<<<splitBlocks, 256, 0, stream>>>(x, bA, bB, N * 128);
  bhist_kernel<<<chunkBlocks, 256, 0, stream>>>(ei, E, bcnt);
  bscan_kernel<<<1, 256, 0, stream>>>(bcnt, bbase, gtail);
  bscatter_kernel<<<chunkBlocks, 256, 0, stream>>>(ei, E, gtail, pair);
  csrbuild_kernel<<<bukBlocks, 256, 0, stream>>>(pair, bbase, ofs, csr, N, E);

  // layer 1: agg1 = sum(x_hi); h1 = relu(x@W1r + agg1@W1n + b1)
  agg_kernel<<<nodeBlocks, 256, 0, stream>>>(bA, csr, ofs, bC, bD, N);
  mgemm_kernel<2, true, true, false><<<gemmBlocks, 512, 0, stream>>>(
      bA, bB, bC, bD, whT, wlT, b1, nullptr, nullptr, nullptr, nullptr,
      bE, bF, N);                                                   // h1 -> E,F

  // layer 2: agg2 = sum(h1_hi); h2 = relu(h1@W2r + agg2@W2n + b2)
  agg_kernel<<<nodeBlocks, 256, 0, stream>>>(bE, csr, ofs, bC, bD, N);
  mgemm_kernel<2, true, true, false><<<gemmBlocks, 512, 0, stream>>>(
      bE, bF, bC, bD, whT + 2 * 16384, wlT + 2 * 16384, b2, nullptr, nullptr,
      nullptr, nullptr, bA, bB, N);                                 // h2 -> A,B

  // attention transform: ht = h2@Wa -> C,D  (+ fused s_src/s_dst dots)
  mgemm_kernel<1, false, false, true><<<gemmBlocks, 512, 0, stream>>>(
      bA, bB, nullptr, nullptr, whT + 4 * 16384, wlT + 4 * 16384, nullptr,
      a_src, a_dst, ssrc, sdst, bC, bD, N);

  // fused attention softmax + PV + FC -> out
  attn_kernel<<<nodeBlocks, 256, 0, stream>>>(
      bC, csr, ofs, ssrc, sdst, Wfc, bfc, (float*)d_out, N);
}

// Round 12
// 252.424 us; speedup vs baseline: 1.7842x; 1.0164x over previous
//
#include <hip/hip_runtime.h>
#include <cstddef>
#include <cstdint>

// ---------------------------------------------------------------------------
// GraphNeuralNetworkRiskManager: 2x GraphConv (sum-agg) + GAT attention + FC
// N=50000 nodes, E=800000 edges, F_IN=HID=128, F_OUT=2.
//
// Round 12 (on round-11 counters: our graph-captured hipMemsetAsync showed as
// a ~40us fillBufferAligned per replay):
//   - memset dispatch deleted; bcnt zeroed by wsplit_kernel block 0 (stream
//     order guarantees it completes before bhist).
//   - CSR intermediate packed to 4B/edge: bucket(7b) | dstLocal(9b) | src(16b)
//     (N=50000 < 2^16) -> halves bscatter/csrbuild pair traffic.
// attn: deg<=64 register softmax, blocks-of-16 PV gathers, fused FC. agg:
// blocks-of-16 masked gathers. GEMMs: bf16x3 MFMA via global_load_lds + XOR
// swizzle; dots fused in Wa-GEMM epilogue. Node tensors bf16 hi+lo pairs.
// ---------------------------------------------------------------------------

typedef __attribute__((ext_vector_type(8))) short short8;
typedef __attribute__((ext_vector_type(4))) float f32x4;

#define NBUK 128
#define BSH  9          // bucket = dst >> 9 (512 nodes per bucket)
#define CHUNK 1568      // edges per bscatter block

__device__ __forceinline__ ushort f2b(float f) {       // fp32 -> bf16 bits, RNE
  uint32_t u = __float_as_uint(f);
  u += 0x7fffu + ((u >> 16) & 1u);
  return (ushort)(u >> 16);
}
__device__ __forceinline__ float b2f(ushort h) {       // bf16 bits -> fp32
  return __uint_as_float(((uint32_t)h) << 16);
}
__device__ __forceinline__ float blo(uint32_t u) { return __uint_as_float(u << 16); }
__device__ __forceinline__ float bhi(uint32_t u) { return __uint_as_float(u & 0xffff0000u); }

__device__ __forceinline__ void gload_lds16(const void* g, void* l) {
  __builtin_amdgcn_global_load_lds(
      (const __attribute__((address_space(1))) void*)g,
      (__attribute__((address_space(3))) void*)l, 16, 0, 0);
}

#define ACC8(A, V)                                     \
  { A[0] += blo(V.x); A[1] += bhi(V.x);                \
    A[2] += blo(V.y); A[3] += bhi(V.y);                \
    A[4] += blo(V.z); A[5] += bhi(V.z);                \
    A[6] += blo(V.w); A[7] += bhi(V.w); }

#define ACC8W(A, V, T)                                 \
  { A[0] += (T) * blo(V.x); A[1] += (T) * bhi(V.x);    \
    A[2] += (T) * blo(V.y); A[3] += (T) * bhi(V.y);    \
    A[4] += (T) * blo(V.z); A[5] += (T) * bhi(V.z);    \
    A[6] += (T) * blo(V.w); A[7] += (T) * bhi(V.w); }

// ---------------- fp32 -> (hi, lo) bf16 split of x ----------------

__global__ __launch_bounds__(256) void split_kernel(
    const float* __restrict__ in, ushort* __restrict__ hi,
    ushort* __restrict__ lo, int n) {
  int i = (blockIdx.x * blockDim.x + threadIdx.x) * 8;
  if (i >= n) return;
  float4 v0 = *(const float4*)(in + i);
  float4 v1 = *(const float4*)(in + i + 4);
  float v[8] = {v0.x, v0.y, v0.z, v0.w, v1.x, v1.y, v1.z, v1.w};
  short8 h, l;
  #pragma unroll
  for (int b = 0; b < 8; ++b) {
    ushort hh = f2b(v[b]);
    h[b] = (short)hh;
    l[b] = (short)f2b(v[b] - b2f(hh));
  }
  *(short8*)(hi + i) = h;
  *(short8*)(lo + i) = l;
}

// ---------------- W split+transpose + bcnt zeroing ----------------
// W[k][j] fp32 -> WhT/WlT[m][j][k] bf16. Block 0 also zeroes bcnt (this
// kernel is first on the stream; bhist runs strictly after it completes).

__global__ __launch_bounds__(256) void wsplit_kernel(
    const float* __restrict__ W0, const float* __restrict__ W1,
    const float* __restrict__ W2, const float* __restrict__ W3,
    const float* __restrict__ W4,
    ushort* __restrict__ WhT, ushort* __restrict__ WlT,
    int* __restrict__ bcnt) {
  __shared__ float tile[128][128];
  int m = blockIdx.x;
  const float* W = (m == 0) ? W0 : (m == 1) ? W1 : (m == 2) ? W2 : (m == 3) ? W3 : W4;
  int t = threadIdx.x;
  if (m == 0 && t < NBUK) bcnt[t] = 0;
  #pragma unroll
  for (int i = 0; i < 64; ++i) {
    int idx = i * 256 + t;                 // coalesced read
    tile[idx >> 7][idx & 127] = W[idx];
  }
  __syncthreads();
  int j = t >> 1, k0 = (t & 1) * 64;
  size_t obase = (size_t)m * 16384 + (size_t)j * 128 + k0;
  #pragma unroll
  for (int c = 0; c < 8; ++c) {
    short8 h, l;
    #pragma unroll
    for (int b = 0; b < 8; ++b) {
      float v = tile[k0 + c * 8 + b][j];
      ushort hh = f2b(v);
      h[b] = (short)hh;
      l[b] = (short)f2b(v - b2f(hh));
    }
    *(short8*)(WhT + obase + c * 8) = h;
    *(short8*)(WlT + obase + c * 8) = l;
  }
}

// ---------------- CSR build, bucketed (packed 4B pair) ----------------
// pk = bucket(7b)<<25 | dstLocal(9b)<<16 | src(16b)

__global__ __launch_bounds__(256) void bhist_kernel(
    const int* __restrict__ ei, int E, int* __restrict__ bcnt) {
  __shared__ int lh[NBUK];
  int t = threadIdx.x;
  if (t < NBUK) lh[t] = 0;
  __syncthreads();
  int base = blockIdx.x * CHUNK;
  int lim = base + CHUNK; if (lim > E) lim = E;
  for (int i = base + t; i < lim; i += 256) atomicAdd(&lh[ei[E + i] >> BSH], 1);
  __syncthreads();
  if (t < NBUK && lh[t]) atomicAdd(&bcnt[t], lh[t]);
}

__global__ __launch_bounds__(256) void bscan_kernel(
    const int* __restrict__ bcnt, int* __restrict__ bbase,
    int* __restrict__ gtail) {
  __shared__ int sA[NBUK], sB[NBUK];
  int t = threadIdx.x;
  if (t < NBUK) sA[t] = bcnt[t];
  __syncthreads();
  int *s = sA, *d = sB;
  for (int st = 1; st < NBUK; st <<= 1) {
    if (t < NBUK) d[t] = s[t] + ((t >= st) ? s[t - st] : 0);
    __syncthreads();
    int* tmp = s; s = d; d = tmp;
  }
  if (t < NBUK) {
    int exc = (t == 0) ? 0 : s[t - 1];
    bbase[t] = exc;
    gtail[t] = exc;
  }
  if (t == 0) bbase[NBUK] = s[NBUK - 1];
}

__global__ __launch_bounds__(256) void bscatter_kernel(
    const int* __restrict__ ei, int E, int* __restrict__ gtail,
    uint* __restrict__ pair) {
  __shared__ int lh[NBUK], sB[NBUK], lofs[NBUK], lcur[NBUK], gbase[NBUK];
  __shared__ uint buf[CHUNK];
  int t = threadIdx.x;
  if (t < NBUK) lh[t] = 0;
  __syncthreads();
  int base = blockIdx.x * CHUNK;
  int lim = base + CHUNK; if (lim > E) lim = E;
  for (int i = base + t; i < lim; i += 256) atomicAdd(&lh[ei[E + i] >> BSH], 1);
  __syncthreads();
  int *s = lh, *d = sB;
  for (int st = 1; st < NBUK; st <<= 1) {
    if (t < NBUK) d[t] = s[t] + ((t >= st) ? s[t - st] : 0);
    __syncthreads();
    int* tmp = s; s = d; d = tmp;
  }
  if (t < NBUK) {
    lofs[t] = (t == 0) ? 0 : s[t - 1];
    lcur[t] = lofs[t];
  }
  __syncthreads();
  for (int i = base + t; i < lim; i += 256) {
    int srcv = ei[i], dstv = ei[E + i];
    int bk = dstv >> BSH;
    int p = atomicAdd(&lcur[bk], 1);
    buf[p] = ((uint)bk << 25) | ((uint)(dstv & ((1 << BSH) - 1)) << 16) | (uint)srcv;
  }
  __syncthreads();
  if (t < NBUK) {
    int c = s[t] - lofs[t];
    gbase[t] = c ? atomicAdd(&gtail[t], c) : 0;
  }
  __syncthreads();
  int n = lim - base;
  for (int i = t; i < n; i += 256) {
    uint pk = buf[i];
    int b = (int)(pk >> 25);
    pair[gbase[b] + (i - lofs[b])] = pk;
  }
}

__global__ __launch_bounds__(256) void csrbuild_kernel(
    const uint* __restrict__ pair, const int* __restrict__ bbase,
    int* __restrict__ ofs, int* __restrict__ csr, int N, int E) {
  __shared__ int hA[512], hB[512];
  int b = blockIdx.x, t = threadIdx.x;
  int base = bbase[b], cnt = bbase[b + 1] - base;
  int node0 = b << BSH;
  int nn = N - node0; if (nn > 512) nn = 512;
  hA[t] = 0; hA[t + 256] = 0;
  __syncthreads();
  for (int i = t; i < cnt; i += 256)
    atomicAdd(&hA[(pair[base + i] >> 16) & 511], 1);
  __syncthreads();
  int *s = hA, *d = hB;
  for (int st = 1; st < 512; st <<= 1) {
    #pragma unroll
    for (int k = 0; k < 2; ++k) {
      int i = t + k * 256;
      d[i] = s[i] + ((i >= st) ? s[i - st] : 0);
    }
    __syncthreads();
    int* tmp = s; s = d; d = tmp;
  }
  #pragma unroll
  for (int k = 0; k < 2; ++k) {
    int i = t + k * 256;
    if (i < nn) ofs[node0 + i] = base + (i == 0 ? 0 : s[i - 1]);
  }
  if (t == 0 && node0 + nn >= N) ofs[N] = E;
  #pragma unroll
  for (int k = 0; k < 2; ++k) {
    int i = t + k * 256;
    d[i] = (i == 0 ? 0 : s[i - 1]);
  }
  __syncthreads();
  for (int i = t; i < cnt; i += 256) {
    uint pk = pair[base + i];
    int p = atomicAdd(&d[(pk >> 16) & 511], 1);
    csr[base + p] = (int)(pk & 0xffffu);
  }
}

// ---------------- CSR sum-aggregation: blocks-of-16 masked gathers ----------------

__global__ __launch_bounds__(256) void agg_kernel(
    const ushort* __restrict__ Xh, const int* __restrict__ csr,
    const int* __restrict__ ofs, ushort* __restrict__ Gh,
    ushort* __restrict__ Gl, int N) {
  int node = (blockIdx.x * blockDim.x + threadIdx.x) >> 6;
  int lane = threadIdx.x & 63;
  if (node >= N) return;
  int g = lane >> 4, q = lane & 15;
  int beg = ofs[node], end = ofs[node + 1];
  int deg = end - beg;
  float a[8] = {};
  for (int base = g; base < deg; base += 16) {
    int ib = base + 4, ic = base + 8, id = base + 12;
    int sa = csr[beg + base];
    int sb = csr[beg + ((ib < deg) ? ib : 0)];
    int sc = csr[beg + ((ic < deg) ? ic : 0)];
    int se = csr[beg + ((id < deg) ? id : 0)];
    uint4 va = *(const uint4*)(Xh + (size_t)sa * 128 + q * 8);
    uint4 vb = *(const uint4*)(Xh + (size_t)sb * 128 + q * 8);
    uint4 vc = *(const uint4*)(Xh + (size_t)sc * 128 + q * 8);
    uint4 vd = *(const uint4*)(Xh + (size_t)se * 128 + q * 8);
    ACC8(a, va);
    if (ib < deg) ACC8(a, vb);
    if (ic < deg) ACC8(a, vc);
    if (id < deg) ACC8(a, vd);
  }
  #pragma unroll
  for (int b = 0; b < 8; ++b) {
    a[b] += __shfl_xor(a[b], 16);
    a[b] += __shfl_xor(a[b], 32);
  }
  if (lane < 16) {
    short8 h, l;
    #pragma unroll
    for (int b = 0; b < 8; ++b) {
      ushort hh = f2b(a[b]);
      h[b] = (short)hh;
      l[b] = (short)f2b(a[b] - b2f(hh));
    }
    *(short8*)(Gh + (size_t)node * 128 + q * 8) = h;
    *(short8*)(Gl + (size_t)node * 128 + q * 8) = l;
  }
}

// ---------------- bf16x3 MFMA GEMM, LDS-staged; optional fused dots ----------------

template <int S, bool RELU, bool BIAS, bool DOTS>
__global__ __launch_bounds__(512, 2) void mgemm_kernel(
    const ushort* __restrict__ A1h, const ushort* __restrict__ A1l,
    const ushort* __restrict__ A2h, const ushort* __restrict__ A2l,
    const ushort* __restrict__ WhT, const ushort* __restrict__ WlT,
    const float* __restrict__ bias,
    const float* __restrict__ asp, const float* __restrict__ adp,
    float* __restrict__ ssrc, float* __restrict__ sdst,
    ushort* __restrict__ Ch, ushort* __restrict__ Cl, int M) {
  __shared__ char lds[2 * S * 16384];   // 2S tiles of 16 KB (64 rows x 256 B)
  __shared__ float pm[DOTS ? 8 * 128 : 1];
  int t = threadIdx.x;
  int l = t & 63;
  int w = t >> 6;
  int j = (w << 4) + (l & 15);      // output column
  int krow0 = (l >> 4) * 8;         // k offset within 32-wide k-step
  int rowBase = blockIdx.x * 64;

  const ushort* srcs[4] = {A1h, A1l, (S > 1) ? A2h : A1h, (S > 1) ? A2l : A1l};
  int ldsWaveBase0 = (t & ~63) * 16;             // uniform per wave, part 0
  #pragma unroll
  for (int q = 0; q < 2 * S; ++q) {
    const char* gsrc = (const char*)srcs[q];
    #pragma unroll
    for (int part = 0; part < 2; ++part) {
      int c = part * 512 + t;                    // chunk id 0..1023
      int r = c >> 4;                            // tile row
      int cb = (c & 15) << 4;                    // byte col within row
      int row = rowBase + r;
      if (row >= M) row = M - 1;
      int sb = cb ^ ((r & 7) << 4);              // inverse-swizzled source col
      gload_lds16(gsrc + (size_t)row * 256 + sb,
                  &lds[q * 16384 + part * 8192 + ldsWaveBase0]);
    }
  }

  short8 wh[S][4], wl[S][4];
  #pragma unroll
  for (int s = 0; s < S; ++s) {
    #pragma unroll
    for (int ks = 0; ks < 4; ++ks) {
      size_t wb = (size_t)s * 16384 + (size_t)j * 128 + ks * 32 + krow0;
      wh[s][ks] = *(const short8*)(WhT + wb);
      wl[s][ks] = *(const short8*)(WlT + wb);
    }
  }

  __syncthreads();   // drains vmcnt (global_load_lds)

  f32x4 acc[4];
  #pragma unroll
  for (int i = 0; i < 4; ++i) acc[i] = (f32x4){0.f, 0.f, 0.f, 0.f};

  #pragma unroll
  for (int rf = 0; rf < 4; ++rf) {
    int r = rf * 16 + (l & 15);
    int sw = (r & 7) << 4;
    int rb = r * 256;
    #pragma unroll
    for (int s = 0; s < S; ++s) {
      #pragma unroll
      for (int ks = 0; ks < 4; ++ks) {
        int off = rb + ((ks * 64 + (l >> 4) * 16) ^ sw);
        short8 ah = *(const short8*)&lds[(s * 2 + 0) * 16384 + off];
        short8 al = *(const short8*)&lds[(s * 2 + 1) * 16384 + off];
        acc[rf] = __builtin_amdgcn_mfma_f32_16x16x32_bf16(al, wh[s][ks], acc[rf], 0, 0, 0);
        acc[rf] = __builtin_amdgcn_mfma_f32_16x16x32_bf16(ah, wl[s][ks], acc[rf], 0, 0, 0);
        acc[rf] = __builtin_amdgcn_mfma_f32_16x16x32_bf16(ah, wh[s][ks], acc[rf], 0, 0, 0);
      }
    }
  }

  float bj = BIAS ? bias[j] : 0.f;
  #pragma unroll
  for (int rf = 0; rf < 4; ++rf) {
    int rbase = rowBase + rf * 16 + (l >> 4) * 4;
    #pragma unroll
    for (int r = 0; r < 4; ++r) {
      int row = rbase + r;
      if (row < M) {
        float v = acc[rf][r];
        if (BIAS) v += bj;
        if (RELU) v = fmaxf(v, 0.f);
        ushort h = f2b(v);
        Ch[(size_t)row * 128 + j] = h;
        Cl[(size_t)row * 128 + j] = f2b(v - b2f(h));
      }
    }
  }

  if constexpr (DOTS) {
    float as_ = asp[j], ad_ = adp[j];
    #pragma unroll
    for (int rf = 0; rf < 4; ++rf) {
      #pragma unroll
      for (int r = 0; r < 4; ++r) {
        float v = acc[rf][r];
        float vs = v * as_, vd = v * ad_;
        #pragma unroll
        for (int d = 1; d < 16; d <<= 1) {
          vs += __shfl_xor(vs, d);
          vd += __shfl_xor(vd, d);
        }
        if ((l & 15) == 0) {
          int rl = rf * 16 + (l >> 4) * 4 + r;
          pm[w * 128 + rl * 2 + 0] = vs;
          pm[w * 128 + rl * 2 + 1] = vd;
        }
      }
    }
    __syncthreads();
    if (t < 64) {
      int row = rowBase + t;
      if (row < M) {
        float vs = 0.f, vd = 0.f;
        #pragma unroll
        for (int ww = 0; ww < 8; ++ww) {
          vs += pm[ww * 128 + t * 2 + 0];
          vd += pm[ww * 128 + t * 2 + 1];
        }
        ssrc[row] = vs;
        sdst[row] = vd;
      }
    }
  }
}

// ---------------- fused attention + FC ----------------
// deg<=64 fast path: lane i owns edge i -- register softmax, then PV with a
// WAVE-UNIFORM trip count (all lanes run all iterations; shfl sources always
// active; per-slot weights masked to 0). deg>64 fallback: 3-pass recompute.

__global__ __launch_bounds__(256) void attn_kernel(
    const ushort* __restrict__ HTh, const int* __restrict__ csr,
    const int* __restrict__ ofs, const float* __restrict__ ssrc,
    const float* __restrict__ sdst, const float* __restrict__ Wfc,
    const float* __restrict__ bfc, float* __restrict__ out, int N) {
  int n = (blockIdx.x * blockDim.x + threadIdx.x) >> 6;
  int lane = threadIdx.x & 63;
  if (n >= N) return;
  int beg = ofs[n], end = ofs[n + 1];
  int deg = end - beg;
  float sd = sdst[n];
  int g = lane >> 4, q = lane & 15;
  float a[8] = {};
  float inv = 0.f;

  if (deg > 0 && deg <= 64) {
    // register softmax: lane i holds edge beg+i
    int s_ = csr[beg + ((lane < deg) ? lane : 0)];
    float e = ssrc[s_] + sd;
    e = (e >= 0.f) ? e : 0.2f * e;
    float m = (lane < deg) ? e : -3.4e38f;
    #pragma unroll
    for (int d = 32; d > 0; d >>= 1) m = fmaxf(m, __shfl_xor(m, d));
    float t = (lane < deg) ? __expf(e - m) : 0.f;
    float ssum = t;
    #pragma unroll
    for (int d = 32; d > 0; d >>= 1) ssum += __shfl_xor(ssum, d);
    inv = 1.0f / (ssum + 1e-16f);

    // PV: uniform trip count -> no divergence around __shfl
    int trips = (deg + 15) >> 4;
    for (int k = 0; k < trips; ++k) {
      int ia = k * 16 + g;
      int ib = ia + 4, ic = ia + 8, id = ia + 12;
      int sa = __shfl(s_, ia & 63);
      int sb = __shfl(s_, ib & 63);
      int sc = __shfl(s_, ic & 63);
      int se = __shfl(s_, id & 63);
      float ta0 = __shfl(t, ia & 63);
      float tb0 = __shfl(t, ib & 63);
      float tc0 = __shfl(t, ic & 63);
      float td0 = __shfl(t, id & 63);
      float ta = (ia < deg) ? ta0 : 0.f;
      float tb = (ib < deg) ? tb0 : 0.f;
      float tc = (ic < deg) ? tc0 : 0.f;
      float td = (id < deg) ? td0 : 0.f;
      uint4 va = *(const uint4*)(HTh + (size_t)sa * 128 + q * 8);
      uint4 vb = *(const uint4*)(HTh + (size_t)sb * 128 + q * 8);
      uint4 vc = *(const uint4*)(HTh + (size_t)sc * 128 + q * 8);
      uint4 vd = *(const uint4*)(HTh + (size_t)se * 128 + q * 8);
      ACC8W(a, va, ta);
      ACC8W(a, vb, tb);
      ACC8W(a, vc, tc);
      ACC8W(a, vd, td);
    }
  } else if (deg > 64) {
    // fallback: 3-pass with recompute
    float m = -3.4e38f;
    for (int i = lane; i < deg; i += 64) {
      float e = ssrc[csr[beg + i]] + sd;
      e = (e >= 0.f) ? e : 0.2f * e;
      m = fmaxf(m, e);
    }
    #pragma unroll
    for (int d = 32; d > 0; d >>= 1) m = fmaxf(m, __shfl_xor(m, d));
    float ssum = 0.f;
    for (int i = lane; i < deg; i += 64) {
      float e = ssrc[csr[beg + i]] + sd;
      e = (e >= 0.f) ? e : 0.2f * e;
      ssum += __expf(e - m);
    }
    #pragma unroll
    for (int d = 32; d > 0; d >>= 1) ssum += __shfl_xor(ssum, d);
    inv = 1.0f / (ssum + 1e-16f);
    for (int i = g; i < deg; i += 4) {
      int s = csr[beg + i];
      float e = ssrc[s] + sd;
      e = (e >= 0.f) ? e : 0.2f * e;
      float t = __expf(e - m);
      uint4 v = *(const uint4*)(HTh + (size_t)s * 128 + q * 8);
      ACC8W(a, v, t);
    }
  }

  #pragma unroll
  for (int b = 0; b < 8; ++b) {
    a[b] += __shfl_xor(a[b], 16);
    a[b] += __shfl_xor(a[b], 32);
    a[b] *= inv;                    // normalize once (deg==0: a stays 0)
  }

  // fused FC: lane q holds outh[n][q*8 .. q*8+7]; Wfc rows are [128][2]
  float4 wf0 = *(const float4*)(Wfc + q * 16);
  float4 wf1 = *(const float4*)(Wfc + q * 16 + 4);
  float4 wf2 = *(const float4*)(Wfc + q * 16 + 8);
  float4 wf3 = *(const float4*)(Wfc + q * 16 + 12);
  float o0 = a[0] * wf0.x + a[1] * wf0.z + a[2] * wf1.x + a[3] * wf1.z +
             a[4] * wf2.x + a[5] * wf2.z + a[6] * wf3.x + a[7] * wf3.z;
  float o1 = a[0] * wf0.y + a[1] * wf0.w + a[2] * wf1.y + a[3] * wf1.w +
             a[4] * wf2.y + a[5] * wf2.w + a[6] * wf3.y + a[7] * wf3.w;
  #pragma unroll
  for (int d = 1; d < 16; d <<= 1) {
    o0 += __shfl_xor(o0, d);
    o1 += __shfl_xor(o1, d);
  }
  if (lane == 0) {
    out[(size_t)n * 2 + 0] = o0 + bfc[0];
    out[(size_t)n * 2 + 1] = o1 + bfc[1];
  }
}

// ---------------- launch ----------------

static inline size_t align_up(size_t x, size_t a) { return (x + a - 1) & ~(a - 1); }

extern "C" void kernel_launch(void* const* d_in, const int* in_sizes, int n_in,
                              void* d_out, int out_size, void* d_ws, size_t ws_size,
                              hipStream_t stream) {
  const float* x     = (const float*)d_in[0];
  const int*   ei    = (const int*)d_in[1];
  const float* W1r   = (const float*)d_in[2];
  const float* W1n   = (const float*)d_in[3];
  const float* b1    = (const float*)d_in[4];
  const float* W2r   = (const float*)d_in[5];
  const float* W2n   = (const float*)d_in[6];
  const float* b2    = (const float*)d_in[7];
  const float* Wa    = (const float*)d_in[8];
  const float* a_src = (const float*)d_in[9];
  const float* a_dst = (const float*)d_in[10];
  const float* Wfc   = (const float*)d_in[11];
  const float* bfc   = (const float*)d_in[12];

  const int N = in_sizes[0] / 128;   // 50000
  const int E = in_sizes[1] / 2;     // 800000

  // workspace carve-up
  char* ws = (char*)d_ws;
  size_t off = 0;
  auto take = [&](size_t bytes) {
    char* p = ws + off;
    off = align_up(off + bytes, 256);
    return p;
  };
  const size_t NB = (size_t)N * 128 * 2;  // one bf16 node tensor (12.8 MB)
  int*    ofs   = (int*)take((size_t)(N + 1) * 4);
  int*    csr   = (int*)take((size_t)E * 4);
  int*    bcnt  = (int*)take(NBUK * 4);
  int*    bbase = (int*)take((NBUK + 1) * 4);
  int*    gtail = (int*)take(NBUK * 4);
  uint*   pair  = (uint*)take((size_t)E * 4);
  float*  ssrc  = (float*)take((size_t)N * 4);
  float*  sdst  = (float*)take((size_t)N * 4);
  ushort* whT   = (ushort*)take((size_t)5 * 16384 * 2);  // pre-split W hi
  ushort* wlT   = (ushort*)take((size_t)5 * 16384 * 2);  // pre-split W lo
  ushort* bA    = (ushort*)take(NB);   // x_hi  -> h2_hi
  ushort* bB    = (ushort*)take(NB);   // x_lo  -> h2_lo
  ushort* bC    = (ushort*)take(NB);   // g_hi  -> ht_hi
  ushort* bD    = (ushort*)take(NB);   // g_lo  -> ht_lo
  ushort* bE    = (ushort*)take(NB);   // h1_hi
  ushort* bF    = (ushort*)take(NB);   // h1_lo

  const int nodeBlocks = (N + 3) / 4;     // 4 waves per 256-thread block
  const int gemmBlocks = (N + 63) / 64;   // 64-row LDS-staged tiles
  const int splitBlocks = (N * 128 / 8 + 255) / 256;
  const int chunkBlocks = (E + CHUNK - 1) / CHUNK;
  const int bukBlocks   = (N + 511) / 512;

  // W pre-split (mats: 0=W1r 1=W1n 2=W2r 3=W2n 4=Wa) + bcnt zeroing;
  // x split; CSR build (no memset dispatch -- round-12 change)
  wsplit_kernel<<<5, 256, 0, stream>>>(W1r, W1n, W2r, W2n, Wa, whT, wlT, bcnt);
  split_kernel<<<splitBlocks, 256, 0, stream>>>(x, bA, bB, N * 128);
  bhist_kernel<<<chunkBlocks, 256, 0, stream>>>(ei, E, bcnt);
  bscan_kernel<<<1, 256, 0, stream>>>(bcnt, bbase, gtail);
  bscatter_kernel<<<chunkBlocks, 256, 0, stream>>>(ei, E, gtail, pair);
  csrbuild_kernel<<<bukBlocks, 256, 0, stream>>>(pair, bbase, ofs, csr, N, E);

  // layer 1: agg1 = sum(x_hi); h1 = relu(x@W1r + agg1@W1n + b1)
  agg_kernel<<<nodeBlocks, 256, 0, stream>>>(bA, csr, ofs, bC, bD, N);
  mgemm_kernel<2, true, true, false><<<gemmBlocks, 512, 0, stream>>>(
      bA, bB, bC, bD, whT, wlT, b1, nullptr, nullptr, nullptr, nullptr,
      bE, bF, N);                                                   // h1 -> E,F

  // layer 2: agg2 = sum(h1_hi); h2 = relu(h1@W2r + agg2@W2n + b2)
  agg_kernel<<<nodeBlocks, 256, 0, stream>>>(bE, csr, ofs, bC, bD, N);
  mgemm_kernel<2, true, true, false><<<gemmBlocks, 512, 0, stream>>>(
      bE, bF, bC, bD, whT + 2 * 16384, wlT + 2 * 16384, b2, nullptr, nullptr,
      nullptr, nullptr, bA, bB, N);                                 // h2 -> A,B

  // attention transform: ht = h2@Wa -> C,D  (+ fused s_src/s_dst dots)
  mgemm_kernel<1, false, false, true><<<gemmBlocks, 512, 0, stream>>>(
      bA, bB, nullptr, nullptr, whT + 4 * 16384, wlT + 4 * 16384, nullptr,
      a_src, a_dst, ssrc, sdst, bC, bD, N);

  // fused attention softmax + PV + FC -> out
  attn_kernel<<<nodeBlocks, 256, 0, stream>>>(
      bC, csr, ofs, ssrc, sdst, Wfc, bfc, (float*)d_out, N);
}